// Round 6
// baseline (289.452 us; speedup 1.0000x reference)
//
#include <hip/hip_runtime.h>
#include <math.h>

#define BB 32
#define PP 32768
#define OO 50
#define NC 21
#define MPT 4            // priors per thread in match_kernel

// level-1 histogram window: float exponents [104,136) -> top16 in [WBINLO, WBINLO+WBINS)
// covers values [5.9e-8, 256) — all realizable ce; bin 0 = zeros; clamp outside.
#define WBINLO (104 << 7)
#define WBINS  4096
#define NWH    4352      // 17*256 (bins 0..4096 used; rest stay zero)

typedef unsigned long long u64;
typedef unsigned int u32;
typedef unsigned char u8;

// workspace: zero-init block first (one small memset), then scratch
static constexpr size_t OFF_WH    = 0;                            // u32[BB*NWH] 557 KB
static constexpr size_t OFF_KEYS  = OFF_WH   + 4ull*BB*NWH;       // u64[BB*OO]
static constexpr size_t OFF_NPOS  = OFF_KEYS + 8ull*BB*OO;        // int[BB]
static constexpr size_t OFF_CCNT  = OFF_NPOS + 128;               // u32[BB] compact counts
static constexpr size_t OFF_DACC  = OFF_CCNT + 128;               // double[3*BB]
static constexpr size_t ZERO_BYTES = OFF_DACC + 8ull*3*BB;
static constexpr size_t OFF_BTOV  = (ZERO_BYTES + 127) & ~127ull; // float[BB*PP]
static constexpr size_t OFF_BTIDX = OFF_BTOV  + 4ull*BB*PP;       // u8[BB*PP]
static constexpr size_t OFF_CEM   = OFF_BTIDX + 1ull*BB*PP;       // float[BB*PP]
static constexpr size_t OFF_CMP   = OFF_CEM   + 4ull*BB*PP;       // u32[BB*PP] boundary list
static constexpr size_t OFF_SELA  = OFF_CMP   + 4ull*BB*PP;       // u32[BB] strict-above cut
static constexpr size_t OFF_SELE  = OFF_SELA  + 128;              // u32[BB] boundary t16
static constexpr size_t OFF_SELK  = OFF_SELE  + 128;              // int[BB] residual k

static __device__ __forceinline__ float fast_div(float a, float b) {
    return a * __builtin_amdgcn_rcpf(b);
}

// Per (b, 4 priors): IoU vs all 50 truths; per-prior argmax thread-local,
// per-truth argmax via float butterfly + ordered ballots (smallest p wins).
__global__ __launch_bounds__(256) void match_kernel(
    const float* __restrict__ priors, const float* __restrict__ targets,
    float* __restrict__ btov, u8* __restrict__ btidx, u64* __restrict__ keys)
{
#pragma clang fp contract(off)
    const int b = blockIdx.y;
    const int tid = threadIdx.x;
    const int lane = tid & 63, wid = tid >> 6;
    const int wbase = blockIdx.x * (256 * MPT) + wid * (64 * MPT);

    __shared__ float tr[OO * 5];
    __shared__ u64 wkeys[4][OO];
    if (tid < OO * 5) tr[tid] = targets[(size_t)b * OO * 5 + tid];
    __syncthreads();

    float px1[MPT], py1[MPT], px2[MPT], py2[MPT], area_p[MPT];
#pragma unroll
    for (int s = 0; s < MPT; ++s) {
        int p = wbase + s * 64 + lane;
        float4 pr = *(const float4*)(priors + (size_t)p * 4);
        px1[s] = pr.x - pr.z * 0.5f; py1[s] = pr.y - pr.w * 0.5f;
        px2[s] = pr.x + pr.z * 0.5f; py2[s] = pr.y + pr.w * 0.5f;
        area_p[s] = (px2[s] - px1[s]) * (py2[s] - py1[s]);
    }

    float bestv[MPT]; int besto[MPT];
#pragma unroll
    for (int s = 0; s < MPT; ++s) { bestv[s] = -1.0f; besto[s] = 0; }

    for (int o = 0; o < OO; ++o) {
        float tx1 = tr[o*5+0], ty1 = tr[o*5+1], tx2 = tr[o*5+2], ty2 = tr[o*5+3];
        float area_t = (tx2 - tx1) * (ty2 - ty1);
        float iou[MPT];
#pragma unroll
        for (int s = 0; s < MPT; ++s) {
            float ix1 = fmaxf(tx1, px1[s]), iy1 = fmaxf(ty1, py1[s]);
            float ix2 = fminf(tx2, px2[s]), iy2 = fminf(ty2, py2[s]);
            float dx = fmaxf(ix2 - ix1, 0.0f), dy = fmaxf(iy2 - iy1, 0.0f);
            float inter = dx * dy;
            iou[s] = fast_div(inter, (area_t + area_p[s]) - inter);
            if (iou[s] > bestv[s]) { bestv[s] = iou[s]; besto[s] = o; }
        }
        float mv = fmaxf(fmaxf(iou[0], iou[1]), fmaxf(iou[2], iou[3]));
        for (int m = 1; m < 64; m <<= 1)
            mv = fmaxf(mv, __shfl_xor(mv, m, 64));
        u64 b0 = __ballot(iou[0] == mv);
        u64 b1 = __ballot(iou[1] == mv);
        u64 b2 = __ballot(iou[2] == mv);
        u64 b3 = __ballot(iou[3] == mv);
        if (lane == 0) {
            int s, l;
            if      (b0) { s = 0; l = __ffsll(b0) - 1; }
            else if (b1) { s = 1; l = __ffsll(b1) - 1; }
            else if (b2) { s = 2; l = __ffsll(b2) - 1; }
            else if (b3) { s = 3; l = __ffsll(b3) - 1; }
            else         { s = 0; l = 0; }
            u32 wp = (u32)(wbase + s * 64 + l);
            wkeys[wid][o] = ((u64)__float_as_uint(mv) << 32) | (u64)(0xFFFFFFFFu - wp);
        }
    }
#pragma unroll
    for (int s = 0; s < MPT; ++s) {
        int p = wbase + s * 64 + lane;
        btov[(size_t)b * PP + p] = bestv[s];
        btidx[(size_t)b * PP + p] = (u8)besto[s];
    }
    __syncthreads();
    if (tid < OO) {
        u64 k0 = wkeys[0][tid];
        for (int w = 1; w < 4; ++w) { u64 kw = wkeys[w][tid]; if (kw > k0) k0 = kw; }
        atomicMax(&keys[b * OO + tid], k0);
    }
}

// Parallel last-wins scatter (numpy fancy-assignment semantics).
__global__ void override_kernel(const u64* __restrict__ keys,
                                float* __restrict__ btov, u8* __restrict__ btidx) {
    const int b = blockIdx.x;
    const int o = threadIdx.x;
    u32 p = 0xFFFFFFFFu;
    if (o < OO) p = 0xFFFFFFFFu - (u32)(keys[b * OO + o] & 0xFFFFFFFFull);
    bool win = (o < OO);
    for (int o2 = 1; o2 < OO; ++o2) {
        u32 p2 = __shfl(p, o2, 64);
        if (o < o2 && p2 == p) win = false;
    }
    if (win) {
        btov[(size_t)b * PP + p] = 2.0f;
        btidx[(size_t)b * PP + p] = (u8)o;
    }
}

static __device__ __forceinline__ u32 top16bits(float v) {
    u32 u = __float_as_uint(v);
    return (v > 0.0f) ? u : 0u;
}

__global__ __launch_bounds__(256) void score_kernel(
    const float* __restrict__ loc, const float* __restrict__ conf,
    const float* __restrict__ priors, const float* __restrict__ targets,
    const float* __restrict__ btov, const u8* __restrict__ btidx,
    float* __restrict__ cemine, int* __restrict__ npos, double* __restrict__ dacc,
    u32* __restrict__ wh)
{
    const int b = blockIdx.y;
    const int p0 = blockIdx.x * 256;
    const int p = p0 + threadIdx.x;
    const int tid = threadIdx.x;
    __shared__ float tr[OO * 5];
    __shared__ float scf[256 * NC];        // conf slab; reused for window hist
    if (tid < OO * 5) tr[tid] = targets[(size_t)b * OO * 5 + tid];

    // conf slab via float4: 1344 x16B = 21 KB, fully coalesced
    {
        const float4* cb4 = (const float4*)(conf + ((size_t)b * PP + p0) * NC);
        float4* s4 = (float4*)scf;
#pragma unroll
        for (int j = 0; j < 5; ++j) s4[j * 256 + tid] = cb4[j * 256 + tid];
        if (tid < 64) s4[1280 + tid] = cb4[1280 + tid];
    }
    __syncthreads();

    float ov = btov[(size_t)b * PP + p];
    int o = btidx[(size_t)b * PP + p];
    int conft = 0;
    if (ov >= 0.5f) conft = (int)(tr[o*5+4] + 1.0f);
    bool pos = conft > 0;

    const float* row = scf + tid * NC;     // stride 21 -> 2-way bank alias, free
    float m = -1e30f;
#pragma unroll
    for (int c = 0; c < NC; ++c) m = fmaxf(m, row[c]);
    float s = 0.0f, tl = 0.0f;
#pragma unroll
    for (int c = 0; c < NC; ++c) { s += expf(row[c] - m); if (c == conft) tl = row[c]; }
    float ce = (m + logf(s)) - tl;

    float cev = pos ? 0.0f : ce;
    cemine[(size_t)b * PP + p] = cev;

    double l_l = 0.0, pce = 0.0; int np_ = 0;
    if (pos) {
        np_ = 1; pce = (double)ce;
        float mx1 = tr[o*5+0], my1 = tr[o*5+1], mx2 = tr[o*5+2], my2 = tr[o*5+3];
        float4 pr = *(const float4*)(priors + (size_t)p * 4);
        float lt0 = ((mx1 + mx2) * 0.5f - pr.x) / (0.1f * pr.z);
        float lt1 = ((my1 + my2) * 0.5f - pr.y) / (0.1f * pr.w);
        float lt2 = logf((mx2 - mx1) / pr.z) / 0.2f;
        float lt3 = logf((my2 - my1) / pr.w) / 0.2f;
        const float* lp = loc + ((size_t)b * PP + p) * 4;
        float lt[4] = {lt0, lt1, lt2, lt3};
#pragma unroll
        for (int i2 = 0; i2 < 4; ++i2) {
            float d = lp[i2] - lt[i2];
            float ad = fabsf(d);
            l_l += (double)(ad < 1.0f ? 0.5f * d * d : ad - 0.5f);
        }
    }
    // wave-level reduction; positives sparse -> most waves issue 0 atomics
    for (int mm = 1; mm < 64; mm <<= 1) {
        l_l += __shfl_xor(l_l, mm, 64);
        pce += __shfl_xor(pce, mm, 64);
        np_ += __shfl_xor(np_, mm, 64);
    }
    if ((tid & 63) == 0) {
        if (l_l != 0.0) atomicAdd(&dacc[b], l_l);
        if (pce != 0.0) atomicAdd(&dacc[BB + b], pce);
        if (np_)        atomicAdd(&npos[b], np_);
    }

    __syncthreads();                       // done reading scf; reuse as window hist
    u32* hh = (u32*)scf;                   // [WBINS]
#pragma unroll
    for (int j = 0; j < WBINS / 256; ++j) hh[j * 256 + tid] = 0;
    __syncthreads();

    u32 t16 = top16bits(cev) >> 16;
    if (t16 != 0) {
        int widx = (int)t16 - WBINLO;
        widx = widx < 0 ? 0 : (widx > WBINS - 1 ? WBINS - 1 : widx);  // clamp (unreachable)
        atomicAdd(&hh[widx], 1u);
    }
    u64 zb = __ballot(t16 == 0);
    if ((tid & 63) == 0 && zb) atomicAdd(&wh[(size_t)b * NWH], (u32)__popcll(zb));
    __syncthreads();
#pragma unroll
    for (int j = 0; j < WBINS / 256; ++j) {
        u32 c = hh[j * 256 + tid];
        if (c) atomicAdd(&wh[(size_t)b * NWH + 1 + j * 256 + tid], c);
    }
}

// Level-1 select on the 4097-bin window hist: threshold bin + residual count.
__global__ __launch_bounds__(256) void selwin_kernel(
    const u32* __restrict__ wh, const int* __restrict__ npos,
    u32* __restrict__ selA, u32* __restrict__ selE, int* __restrict__ selK)
{
    const int b = blockIdx.x, tid = threadIdx.x;
    const int lane = tid & 63, wid = tid >> 6;
    int k = npos[b] * 3; if (k > PP - 1) k = PP - 1;
    if (k <= 0) {
        if (tid == 0) { selA[b] = 0xFFFFFFFFu; selE[b] = 0xFFFFFFFEu; selK[b] = 0; }
        return;
    }
    const u32* h = wh + (size_t)b * NWH;
    __shared__ u32 chs[17];
    __shared__ u32 ct[256];
    __shared__ int s_cT; __shared__ u32 s_above; __shared__ u32 sT;

    for (int c = wid; c < 17; c += 4) {
        u32 cnt = 0;
#pragma unroll
        for (int q = 0; q < 4; ++q) cnt += h[c * 256 + q * 64 + lane];
        for (int m = 1; m < 64; m <<= 1) cnt += __shfl_xor(cnt, m, 64);
        if (lane == 0) chs[c] = cnt;
    }
    if (tid == 0) sT = 0;
    __syncthreads();
    if (tid == 0) {
        u32 cum = 0; int cT = 0; u32 above = 0;
        for (int c = 16; c >= 0; --c) {
            if (cum + chs[c] >= (u32)k) { cT = c; above = cum; break; }
            cum += chs[c];
        }
        s_cT = cT; s_above = above;
    }
    __syncthreads();
    const int cT = s_cT; const u32 aboveChunk = s_above;
    ct[tid] = h[cT * 256 + tid];
    __syncthreads();
    for (int off = 1; off < 256; off <<= 1) {
        u32 add = (tid + off < 256) ? ct[tid + off] : 0;
        __syncthreads();
        ct[tid] += add;
        __syncthreads();
    }
    if (aboveChunk + ct[tid] >= (u32)k) atomicMax(&sT, (u32)tid);
    __syncthreads();
    const int T = (int)sT;
    if (tid == T) {
        u32 aboveBin = aboveChunk + ((T < 255) ? ct[T + 1] : 0);
        int g = cT * 256 + T;
        if (g == 0) {   // threshold in zeros: take all nonzero, boundary adds ~0
            selA[b] = WBINLO - 1; selE[b] = 0xFFFFFFFEu; selK[b] = 0;
        } else {
            u32 T16 = (u32)(WBINLO + g - 1);
            selA[b] = T16; selE[b] = T16; selK[b] = k - (int)aboveBin;
        }
    }
}

// Data pass: f64-sum values strictly above cut; compact boundary bin elements.
__global__ __launch_bounds__(256) void scan2_kernel(
    const float* __restrict__ cemine, const u32* __restrict__ selA,
    const u32* __restrict__ selE, u32* __restrict__ cmp, u32* __restrict__ ccnt,
    double* __restrict__ dacc)
{
    const int b = blockIdx.y, tid = threadIdx.x;
    const u32 A = selA[b], E = selE[b];
    const float4* v4 = (const float4*)(cemine + (size_t)b * PP);
    float4 f = v4[blockIdx.x * 256 + tid];
    double acc = 0.0;
    float vv[4] = {f.x, f.y, f.z, f.w};
#pragma unroll
    for (int c = 0; c < 4; ++c) {
        u32 u = top16bits(vv[c]);
        u32 hi = u >> 16;
        if (hi > A) acc += (double)vv[c];
        else if (hi == E) {
            u32 idx = atomicAdd(&ccnt[b], 1u);
            cmp[(size_t)b * PP + idx] = u;
        }
    }
    for (int m = 1; m < 64; m <<= 1) acc += __shfl_xor(acc, m, 64);
    if ((tid & 63) == 0 && acc != 0.0) atomicAdd(&dacc[2 * BB + b], acc);
}

// Exact within-bin top-k2 sum from the compacted list: all elements share the
// exponent/top-mantissa, so value = C0 + L*C1 is linear in low16 bits L.
// Two 256-bin LDS passes (high byte of L, then low byte) give the exact sum.
__global__ __launch_bounds__(256) void selfinal_kernel(
    const u32* __restrict__ cmp, const u32* __restrict__ ccnt,
    const u32* __restrict__ selE, const int* __restrict__ selK,
    double* __restrict__ dacc)
{
    const int b = blockIdx.x, tid = threadIdx.x;
    const int k2 = selK[b];
    if (k2 <= 0) return;
    const u32 T16 = selE[b];
    const int n = (int)ccnt[b];
    const u32* lst = cmp + (size_t)b * PP;
    __shared__ u32 hc[256], hl[256];
    __shared__ u32 sT;
    hc[tid] = 0; hl[tid] = 0; if (tid == 0) sT = 0;
    __syncthreads();
    for (int i = tid; i < n; i += 256) {
        u32 L = lst[i] & 0xFFFFu;
        atomicAdd(&hc[L >> 8], 1u);
        atomicAdd(&hl[L >> 8], L);
    }
    __syncthreads();
    for (int off = 1; off < 256; off <<= 1) {
        u32 a1 = (tid + off < 256) ? hc[tid + off] : 0;
        u32 a2 = (tid + off < 256) ? hl[tid + off] : 0;
        __syncthreads();
        hc[tid] += a1; hl[tid] += a2;
        __syncthreads();
    }
    if (hc[tid] >= (u32)k2) atomicMax(&sT, (u32)tid);
    __syncthreads();
    const int B1 = (int)sT;
    const u32 aboveCnt = (B1 < 255) ? hc[B1 + 1] : 0;
    const u32 aboveL   = (B1 < 255) ? hl[B1 + 1] : 0;
    const int k3 = k2 - (int)aboveCnt;
    __syncthreads();
    hc[tid] = 0; if (tid == 0) sT = 0;
    __syncthreads();
    for (int i = tid; i < n; i += 256) {
        u32 L = lst[i] & 0xFFFFu;
        if ((int)(L >> 8) == B1) atomicAdd(&hc[L & 0xFFu], 1u);
    }
    __syncthreads();
    hl[tid] = hc[tid] * (u32)tid;
    __syncthreads();
    for (int off = 1; off < 256; off <<= 1) {
        u32 a1 = (tid + off < 256) ? hc[tid + off] : 0;
        u32 a2 = (tid + off < 256) ? hl[tid + off] : 0;
        __syncthreads();
        hc[tid] += a1; hl[tid] += a2;
        __syncthreads();
    }
    if (hc[tid] >= (u32)k3) atomicMax(&sT, (u32)tid);
    __syncthreads();
    const int B2 = (int)sT;
    if (tid == B2) {
        u32 n2 = (B2 < 255) ? hc[B2 + 1] : 0;
        u32 W2 = (B2 < 255) ? hl[B2 + 1] : 0;
        int teq = k3 - (int)n2;
        double C0 = (double)__uint_as_float(T16 << 16);
        double C1 = (double)__uint_as_float((T16 << 16) | 1u) - C0;
        double Lsum = (double)aboveL + (double)n2 * (double)(B1 << 8) + (double)W2
                    + (double)teq * (double)((B1 << 8) | B2);
        dacc[2 * BB + b] += (double)k2 * C0 + C1 * Lsum;
    }
}

__global__ void finalize_kernel(const int* __restrict__ npos,
                                const double* __restrict__ dacc, float* __restrict__ out) {
    if (threadIdx.x == 0 && blockIdx.x == 0) {
        double N = 0.0, ll = 0.0, lc = 0.0;
        for (int b = 0; b < BB; ++b) {
            N += (double)npos[b];
            ll += dacc[b];
            lc += dacc[BB + b] + dacc[2 * BB + b];
        }
        out[0] = (float)(ll / N);
        out[1] = (float)(lc / N);
    }
}

extern "C" void kernel_launch(void* const* d_in, const int* in_sizes, int n_in,
                              void* d_out, int out_size, void* d_ws, size_t ws_size,
                              hipStream_t stream) {
    const float* loc     = (const float*)d_in[0];
    const float* conf    = (const float*)d_in[1];
    const float* priors  = (const float*)d_in[2];
    const float* targets = (const float*)d_in[3];
    char* ws = (char*)d_ws;
    u32*    wh    = (u32*)   (ws + OFF_WH);
    u64*    keys  = (u64*)   (ws + OFF_KEYS);
    int*    npos  = (int*)   (ws + OFF_NPOS);
    u32*    ccnt  = (u32*)   (ws + OFF_CCNT);
    double* dacc  = (double*)(ws + OFF_DACC);
    float*  btov  = (float*) (ws + OFF_BTOV);
    u8*     btidx = (u8*)    (ws + OFF_BTIDX);
    float*  cem   = (float*) (ws + OFF_CEM);
    u32*    cmp   = (u32*)   (ws + OFF_CMP);
    u32*    selA  = (u32*)   (ws + OFF_SELA);
    u32*    selE  = (u32*)   (ws + OFF_SELE);
    int*    selK  = (int*)   (ws + OFF_SELK);
    float*  out   = (float*)d_out;

    hipMemsetAsync(ws, 0, ZERO_BYTES, stream);   // wh+keys+npos+ccnt+dacc (~0.56 MB)
    match_kernel<<<dim3(PP / (256 * MPT), BB), 256, 0, stream>>>(priors, targets, btov, btidx, keys);
    override_kernel<<<BB, 64, 0, stream>>>(keys, btov, btidx);
    score_kernel<<<dim3(PP / 256, BB), 256, 0, stream>>>(loc, conf, priors, targets, btov, btidx, cem, npos, dacc, wh);
    selwin_kernel<<<BB, 256, 0, stream>>>(wh, npos, selA, selE, selK);
    scan2_kernel<<<dim3(32, BB), 256, 0, stream>>>(cem, selA, selE, cmp, ccnt, dacc);
    selfinal_kernel<<<BB, 256, 0, stream>>>(cmp, ccnt, selE, selK, dacc);
    finalize_kernel<<<1, 64, 0, stream>>>(npos, dacc, out);
}

// Round 7
// 190.419 us; speedup vs baseline: 1.5201x; 1.5201x over previous
//
#include <hip/hip_runtime.h>
#include <math.h>

#define BB 32
#define PP 32768
#define OO 50
#define NC 21
#define MPT 4            // priors per thread in match_kernel

// level-1 histogram window: float exponents [104,136) -> top16 in [WBINLO, WBINLO+WBINS)
// covers values [5.9e-8, 256) — all realizable ce; bin 0 = zeros; clamp outside.
#define WBINLO (104 << 7)
#define WBINS  4096
#define NWH    4352      // 17*256 (bins 0..4096 used; rest stay zero)

typedef unsigned long long u64;
typedef unsigned int u32;
typedef unsigned char u8;

// workspace: zero-init block first (one small memset), then scratch
static constexpr size_t OFF_WH    = 0;                            // u32[BB*NWH] 557 KB
static constexpr size_t OFF_KEYS  = OFF_WH   + 4ull*BB*NWH;       // u64[BB*OO]
static constexpr size_t OFF_NPOS  = OFF_KEYS + 8ull*BB*OO;        // int[BB]
static constexpr size_t OFF_CCNT  = OFF_NPOS + 128;               // u32[BB] compact counts
static constexpr size_t OFF_DACC  = OFF_CCNT + 128;               // double[3*BB]
static constexpr size_t ZERO_BYTES = OFF_DACC + 8ull*3*BB;
static constexpr size_t OFF_BTOV  = (ZERO_BYTES + 127) & ~127ull; // float[BB*PP]
static constexpr size_t OFF_BTIDX = OFF_BTOV  + 4ull*BB*PP;       // u8[BB*PP]
static constexpr size_t OFF_CEM   = OFF_BTIDX + 1ull*BB*PP;       // float[BB*PP]
static constexpr size_t OFF_CMP   = OFF_CEM   + 4ull*BB*PP;       // u32[BB*PP] boundary list
static constexpr size_t OFF_SELA  = OFF_CMP   + 4ull*BB*PP;       // u32[BB] strict-above cut
static constexpr size_t OFF_SELE  = OFF_SELA  + 128;              // u32[BB] boundary t16
static constexpr size_t OFF_SELK  = OFF_SELE  + 128;              // int[BB] residual k

static __device__ __forceinline__ float fast_div(float a, float b) {
    return a * __builtin_amdgcn_rcpf(b);
}

// Per (b, 4 priors): IoU vs all 50 truths; per-prior argmax thread-local,
// per-truth argmax via float butterfly + ordered ballots (smallest p wins).
__global__ __launch_bounds__(256) void match_kernel(
    const float* __restrict__ priors, const float* __restrict__ targets,
    float* __restrict__ btov, u8* __restrict__ btidx, u64* __restrict__ keys)
{
#pragma clang fp contract(off)
    const int b = blockIdx.y;
    const int tid = threadIdx.x;
    const int lane = tid & 63, wid = tid >> 6;
    const int wbase = blockIdx.x * (256 * MPT) + wid * (64 * MPT);

    __shared__ float tr[OO * 5];
    __shared__ u64 wkeys[4][OO];
    if (tid < OO * 5) tr[tid] = targets[(size_t)b * OO * 5 + tid];
    __syncthreads();

    float px1[MPT], py1[MPT], px2[MPT], py2[MPT], area_p[MPT];
#pragma unroll
    for (int s = 0; s < MPT; ++s) {
        int p = wbase + s * 64 + lane;
        float4 pr = *(const float4*)(priors + (size_t)p * 4);
        px1[s] = pr.x - pr.z * 0.5f; py1[s] = pr.y - pr.w * 0.5f;
        px2[s] = pr.x + pr.z * 0.5f; py2[s] = pr.y + pr.w * 0.5f;
        area_p[s] = (px2[s] - px1[s]) * (py2[s] - py1[s]);
    }

    float bestv[MPT]; int besto[MPT];
#pragma unroll
    for (int s = 0; s < MPT; ++s) { bestv[s] = -1.0f; besto[s] = 0; }

    for (int o = 0; o < OO; ++o) {
        float tx1 = tr[o*5+0], ty1 = tr[o*5+1], tx2 = tr[o*5+2], ty2 = tr[o*5+3];
        float area_t = (tx2 - tx1) * (ty2 - ty1);
        float iou[MPT];
#pragma unroll
        for (int s = 0; s < MPT; ++s) {
            float ix1 = fmaxf(tx1, px1[s]), iy1 = fmaxf(ty1, py1[s]);
            float ix2 = fminf(tx2, px2[s]), iy2 = fminf(ty2, py2[s]);
            float dx = fmaxf(ix2 - ix1, 0.0f), dy = fmaxf(iy2 - iy1, 0.0f);
            float inter = dx * dy;
            iou[s] = fast_div(inter, (area_t + area_p[s]) - inter);
            if (iou[s] > bestv[s]) { bestv[s] = iou[s]; besto[s] = o; }
        }
        float mv = fmaxf(fmaxf(iou[0], iou[1]), fmaxf(iou[2], iou[3]));
        for (int m = 1; m < 64; m <<= 1)
            mv = fmaxf(mv, __shfl_xor(mv, m, 64));
        u64 b0 = __ballot(iou[0] == mv);
        u64 b1 = __ballot(iou[1] == mv);
        u64 b2 = __ballot(iou[2] == mv);
        u64 b3 = __ballot(iou[3] == mv);
        if (lane == 0) {
            int s, l;
            if      (b0) { s = 0; l = __ffsll(b0) - 1; }
            else if (b1) { s = 1; l = __ffsll(b1) - 1; }
            else if (b2) { s = 2; l = __ffsll(b2) - 1; }
            else if (b3) { s = 3; l = __ffsll(b3) - 1; }
            else         { s = 0; l = 0; }
            u32 wp = (u32)(wbase + s * 64 + l);
            wkeys[wid][o] = ((u64)__float_as_uint(mv) << 32) | (u64)(0xFFFFFFFFu - wp);
        }
    }
#pragma unroll
    for (int s = 0; s < MPT; ++s) {
        int p = wbase + s * 64 + lane;
        btov[(size_t)b * PP + p] = bestv[s];
        btidx[(size_t)b * PP + p] = (u8)besto[s];
    }
    __syncthreads();
    if (tid < OO) {
        u64 k0 = wkeys[0][tid];
        for (int w = 1; w < 4; ++w) { u64 kw = wkeys[w][tid]; if (kw > k0) k0 = kw; }
        atomicMax(&keys[b * OO + tid], k0);
    }
}

// Parallel last-wins scatter (numpy fancy-assignment semantics).
__global__ void override_kernel(const u64* __restrict__ keys,
                                float* __restrict__ btov, u8* __restrict__ btidx) {
    const int b = blockIdx.x;
    const int o = threadIdx.x;
    u32 p = 0xFFFFFFFFu;
    if (o < OO) p = 0xFFFFFFFFu - (u32)(keys[b * OO + o] & 0xFFFFFFFFull);
    bool win = (o < OO);
    for (int o2 = 1; o2 < OO; ++o2) {
        u32 p2 = __shfl(p, o2, 64);
        if (o < o2 && p2 == p) win = false;
    }
    if (win) {
        btov[(size_t)b * PP + p] = 2.0f;
        btidx[(size_t)b * PP + p] = (u8)o;
    }
}

static __device__ __forceinline__ u32 top16bits(float v) {
    u32 u = __float_as_uint(v);
    return (v > 0.0f) ? u : 0u;
}

// Round-5-proven structure: scalar coalesced conf staging + LDS-tree
// reduction (reused slab), LDS window hist flushed to compact global wh.
__global__ __launch_bounds__(256) void score_kernel(
    const float* __restrict__ loc, const float* __restrict__ conf,
    const float* __restrict__ priors, const float* __restrict__ targets,
    const float* __restrict__ btov, const u8* __restrict__ btidx,
    float* __restrict__ cemine, int* __restrict__ npos, double* __restrict__ dacc,
    u32* __restrict__ wh)
{
    const int b = blockIdx.y;
    const int p0 = blockIdx.x * 256;
    const int p = p0 + threadIdx.x;
    const int tid = threadIdx.x;
    __shared__ float tr[OO * 5];
    __shared__ float scf[256 * NC];        // conf slab; reused for hist + reductions
    if (tid < OO * 5) tr[tid] = targets[(size_t)b * OO * 5 + tid];

    // coalesced conf load: 21 fully-coalesced dword rounds -> LDS row-major
    {
        const float* cb = conf + ((size_t)b * PP + p0) * NC;
#pragma unroll
        for (int j = 0; j < NC; ++j) scf[j * 256 + tid] = cb[j * 256 + tid];
    }
    __syncthreads();

    float ov = btov[(size_t)b * PP + p];
    int o = btidx[(size_t)b * PP + p];
    int conft = 0;
    if (ov >= 0.5f) conft = (int)(tr[o*5+4] + 1.0f);
    bool pos = conft > 0;

    const float* row = scf + tid * NC;     // stride 21 (odd) -> 2-way bank alias, free
    float m = -1e30f;
#pragma unroll
    for (int c = 0; c < NC; ++c) m = fmaxf(m, row[c]);
    float s = 0.0f, tl = 0.0f;
#pragma unroll
    for (int c = 0; c < NC; ++c) { s += expf(row[c] - m); if (c == conft) tl = row[c]; }
    float ce = (m + logf(s)) - tl;

    float cev = pos ? 0.0f : ce;
    cemine[(size_t)b * PP + p] = cev;

    double l_l = 0.0, pce = 0.0; int np_ = 0;
    if (pos) {
        np_ = 1; pce = (double)ce;
        float mx1 = tr[o*5+0], my1 = tr[o*5+1], mx2 = tr[o*5+2], my2 = tr[o*5+3];
        float4 pr = *(const float4*)(priors + (size_t)p * 4);
        float lt0 = ((mx1 + mx2) * 0.5f - pr.x) / (0.1f * pr.z);
        float lt1 = ((my1 + my2) * 0.5f - pr.y) / (0.1f * pr.w);
        float lt2 = logf((mx2 - mx1) / pr.z) / 0.2f;
        float lt3 = logf((my2 - my1) / pr.w) / 0.2f;
        const float* lp = loc + ((size_t)b * PP + p) * 4;
        float lt[4] = {lt0, lt1, lt2, lt3};
#pragma unroll
        for (int i2 = 0; i2 < 4; ++i2) {
            float d = lp[i2] - lt[i2];
            float ad = fabsf(d);
            l_l += (double)(ad < 1.0f ? 0.5f * d * d : ad - 0.5f);
        }
    }

    __syncthreads();                       // done reading scf; reuse the LDS
    u32*    hh = (u32*)scf;                // [WBINS] window histogram (16 KB)
    double* rl = (double*)(scf + WBINS);   // 256 doubles
    double* rc = rl + 256;                 // 256 doubles
    int*    rn = (int*)(rc + 256);         // 256 ints
#pragma unroll
    for (int j = 0; j < WBINS / 256; ++j) hh[j * 256 + tid] = 0;
    rl[tid] = l_l; rc[tid] = pce; rn[tid] = np_;
    __syncthreads();

    // LDS pre-aggregated histogram (exact): window bins in LDS, zeros via
    // ballot+popcount (1 atomic/wave), clamp outside window (unreachable).
    u32 t16 = top16bits(cev) >> 16;
    if (t16 != 0) {
        int widx = (int)t16 - WBINLO;
        widx = widx < 0 ? 0 : (widx > WBINS - 1 ? WBINS - 1 : widx);
        atomicAdd(&hh[widx], 1u);
    }
    u64 zb = __ballot(t16 == 0);
    if ((tid & 63) == 0 && zb) atomicAdd(&wh[(size_t)b * NWH], (u32)__popcll(zb));
    __syncthreads();

    // flush nonzero window bins (~hundreds) + block tree reduction
#pragma unroll
    for (int j = 0; j < WBINS / 256; ++j) {
        u32 c = hh[j * 256 + tid];
        if (c) atomicAdd(&wh[(size_t)b * NWH + 1 + j * 256 + tid], c);
    }
    for (int s2 = 128; s2 > 0; s2 >>= 1) {
        if (tid < s2) { rl[tid] += rl[tid+s2]; rc[tid] += rc[tid+s2]; rn[tid] += rn[tid+s2]; }
        __syncthreads();
    }
    if (tid == 0) {
        atomicAdd(&dacc[b], rl[0]);
        atomicAdd(&dacc[BB + b], rc[0]);
        atomicAdd(&npos[b], rn[0]);
    }
}

// Level-1 select on the 4097-bin window hist: threshold bin + residual count.
__global__ __launch_bounds__(256) void selwin_kernel(
    const u32* __restrict__ wh, const int* __restrict__ npos,
    u32* __restrict__ selA, u32* __restrict__ selE, int* __restrict__ selK)
{
    const int b = blockIdx.x, tid = threadIdx.x;
    const int lane = tid & 63, wid = tid >> 6;
    int k = npos[b] * 3; if (k > PP - 1) k = PP - 1;
    if (k <= 0) {
        if (tid == 0) { selA[b] = 0xFFFFFFFFu; selE[b] = 0xFFFFFFFEu; selK[b] = 0; }
        return;
    }
    const u32* h = wh + (size_t)b * NWH;
    __shared__ u32 chs[17];
    __shared__ u32 ct[256];
    __shared__ int s_cT; __shared__ u32 s_above; __shared__ u32 sT;

    for (int c = wid; c < 17; c += 4) {
        u32 cnt = 0;
#pragma unroll
        for (int q = 0; q < 4; ++q) cnt += h[c * 256 + q * 64 + lane];
        for (int m = 1; m < 64; m <<= 1) cnt += __shfl_xor(cnt, m, 64);
        if (lane == 0) chs[c] = cnt;
    }
    if (tid == 0) sT = 0;
    __syncthreads();
    if (tid == 0) {
        u32 cum = 0; int cT = 0; u32 above = 0;
        for (int c = 16; c >= 0; --c) {
            if (cum + chs[c] >= (u32)k) { cT = c; above = cum; break; }
            cum += chs[c];
        }
        s_cT = cT; s_above = above;
    }
    __syncthreads();
    const int cT = s_cT; const u32 aboveChunk = s_above;
    ct[tid] = h[cT * 256 + tid];
    __syncthreads();
    for (int off = 1; off < 256; off <<= 1) {
        u32 add = (tid + off < 256) ? ct[tid + off] : 0;
        __syncthreads();
        ct[tid] += add;
        __syncthreads();
    }
    if (aboveChunk + ct[tid] >= (u32)k) atomicMax(&sT, (u32)tid);
    __syncthreads();
    const int T = (int)sT;
    if (tid == T) {
        u32 aboveBin = aboveChunk + ((T < 255) ? ct[T + 1] : 0);
        int g = cT * 256 + T;
        if (g == 0) {   // threshold in zeros: take all nonzero, boundary adds ~0
            selA[b] = WBINLO - 1; selE[b] = 0xFFFFFFFEu; selK[b] = 0;
        } else {
            u32 T16 = (u32)(WBINLO + g - 1);
            selA[b] = T16; selE[b] = T16; selK[b] = k - (int)aboveBin;
        }
    }
}

// Data pass: f64-sum values strictly above cut; compact boundary bin elements.
__global__ __launch_bounds__(256) void scan2_kernel(
    const float* __restrict__ cemine, const u32* __restrict__ selA,
    const u32* __restrict__ selE, u32* __restrict__ cmp, u32* __restrict__ ccnt,
    double* __restrict__ dacc)
{
    const int b = blockIdx.y, tid = threadIdx.x;
    const u32 A = selA[b], E = selE[b];
    const float4* v4 = (const float4*)(cemine + (size_t)b * PP);
    float4 f = v4[blockIdx.x * 256 + tid];
    double acc = 0.0;
    float vv[4] = {f.x, f.y, f.z, f.w};
#pragma unroll
    for (int c = 0; c < 4; ++c) {
        u32 u = top16bits(vv[c]);
        u32 hi = u >> 16;
        if (hi > A) acc += (double)vv[c];
        else if (hi == E) {
            u32 idx = atomicAdd(&ccnt[b], 1u);
            cmp[(size_t)b * PP + idx] = u;
        }
    }
    __shared__ double red[256];
    red[tid] = acc;
    __syncthreads();
    for (int s2 = 128; s2 > 0; s2 >>= 1) {
        if (tid < s2) red[tid] += red[tid + s2];
        __syncthreads();
    }
    if (tid == 0 && red[0] != 0.0) atomicAdd(&dacc[2 * BB + b], red[0]);
}

// Exact within-bin top-k2 sum from the compacted list: all elements share the
// exponent/top-mantissa, so value = C0 + L*C1 is linear in low16 bits L.
__global__ __launch_bounds__(256) void selfinal_kernel(
    const u32* __restrict__ cmp, const u32* __restrict__ ccnt,
    const u32* __restrict__ selE, const int* __restrict__ selK,
    double* __restrict__ dacc)
{
    const int b = blockIdx.x, tid = threadIdx.x;
    const int k2 = selK[b];
    if (k2 <= 0) return;
    const u32 T16 = selE[b];
    const int n = (int)ccnt[b];
    const u32* lst = cmp + (size_t)b * PP;
    __shared__ u32 hc[256], hl[256];
    __shared__ u32 sT;
    hc[tid] = 0; hl[tid] = 0; if (tid == 0) sT = 0;
    __syncthreads();
    for (int i = tid; i < n; i += 256) {
        u32 L = lst[i] & 0xFFFFu;
        atomicAdd(&hc[L >> 8], 1u);
        atomicAdd(&hl[L >> 8], L);
    }
    __syncthreads();
    for (int off = 1; off < 256; off <<= 1) {
        u32 a1 = (tid + off < 256) ? hc[tid + off] : 0;
        u32 a2 = (tid + off < 256) ? hl[tid + off] : 0;
        __syncthreads();
        hc[tid] += a1; hl[tid] += a2;
        __syncthreads();
    }
    if (hc[tid] >= (u32)k2) atomicMax(&sT, (u32)tid);
    __syncthreads();
    const int B1 = (int)sT;
    const u32 aboveCnt = (B1 < 255) ? hc[B1 + 1] : 0;
    const u32 aboveL   = (B1 < 255) ? hl[B1 + 1] : 0;
    const int k3 = k2 - (int)aboveCnt;
    __syncthreads();
    hc[tid] = 0; if (tid == 0) sT = 0;
    __syncthreads();
    for (int i = tid; i < n; i += 256) {
        u32 L = lst[i] & 0xFFFFu;
        if ((int)(L >> 8) == B1) atomicAdd(&hc[L & 0xFFu], 1u);
    }
    __syncthreads();
    hl[tid] = hc[tid] * (u32)tid;
    __syncthreads();
    for (int off = 1; off < 256; off <<= 1) {
        u32 a1 = (tid + off < 256) ? hc[tid + off] : 0;
        u32 a2 = (tid + off < 256) ? hl[tid + off] : 0;
        __syncthreads();
        hc[tid] += a1; hl[tid] += a2;
        __syncthreads();
    }
    if (hc[tid] >= (u32)k3) atomicMax(&sT, (u32)tid);
    __syncthreads();
    const int B2 = (int)sT;
    if (tid == B2) {
        u32 n2 = (B2 < 255) ? hc[B2 + 1] : 0;
        u32 W2 = (B2 < 255) ? hl[B2 + 1] : 0;
        int teq = k3 - (int)n2;
        double C0 = (double)__uint_as_float(T16 << 16);
        double C1 = (double)__uint_as_float((T16 << 16) | 1u) - C0;
        double Lsum = (double)aboveL + (double)n2 * (double)(B1 << 8) + (double)W2
                    + (double)teq * (double)((B1 << 8) | B2);
        dacc[2 * BB + b] += (double)k2 * C0 + C1 * Lsum;
    }
}

__global__ void finalize_kernel(const int* __restrict__ npos,
                                const double* __restrict__ dacc, float* __restrict__ out) {
    if (threadIdx.x == 0 && blockIdx.x == 0) {
        double N = 0.0, ll = 0.0, lc = 0.0;
        for (int b = 0; b < BB; ++b) {
            N += (double)npos[b];
            ll += dacc[b];
            lc += dacc[BB + b] + dacc[2 * BB + b];
        }
        out[0] = (float)(ll / N);
        out[1] = (float)(lc / N);
    }
}

extern "C" void kernel_launch(void* const* d_in, const int* in_sizes, int n_in,
                              void* d_out, int out_size, void* d_ws, size_t ws_size,
                              hipStream_t stream) {
    const float* loc     = (const float*)d_in[0];
    const float* conf    = (const float*)d_in[1];
    const float* priors  = (const float*)d_in[2];
    const float* targets = (const float*)d_in[3];
    char* ws = (char*)d_ws;
    u32*    wh    = (u32*)   (ws + OFF_WH);
    u64*    keys  = (u64*)   (ws + OFF_KEYS);
    int*    npos  = (int*)   (ws + OFF_NPOS);
    u32*    ccnt  = (u32*)   (ws + OFF_CCNT);
    double* dacc  = (double*)(ws + OFF_DACC);
    float*  btov  = (float*) (ws + OFF_BTOV);
    u8*     btidx = (u8*)    (ws + OFF_BTIDX);
    float*  cem   = (float*) (ws + OFF_CEM);
    u32*    cmp   = (u32*)   (ws + OFF_CMP);
    u32*    selA  = (u32*)   (ws + OFF_SELA);
    u32*    selE  = (u32*)   (ws + OFF_SELE);
    int*    selK  = (int*)   (ws + OFF_SELK);
    float*  out   = (float*)d_out;

    hipMemsetAsync(ws, 0, ZERO_BYTES, stream);   // wh+keys+npos+ccnt+dacc (~0.56 MB)
    match_kernel<<<dim3(PP / (256 * MPT), BB), 256, 0, stream>>>(priors, targets, btov, btidx, keys);
    override_kernel<<<BB, 64, 0, stream>>>(keys, btov, btidx);
    score_kernel<<<dim3(PP / 256, BB), 256, 0, stream>>>(loc, conf, priors, targets, btov, btidx, cem, npos, dacc, wh);
    selwin_kernel<<<BB, 256, 0, stream>>>(wh, npos, selA, selE, selK);
    scan2_kernel<<<dim3(32, BB), 256, 0, stream>>>(cem, selA, selE, cmp, ccnt, dacc);
    selfinal_kernel<<<BB, 256, 0, stream>>>(cmp, ccnt, selE, selK, dacc);
    finalize_kernel<<<1, 64, 0, stream>>>(npos, dacc, out);
}

// Round 8
// 168.733 us; speedup vs baseline: 1.7154x; 1.1285x over previous
//
#include <hip/hip_runtime.h>
#include <math.h>

#define BB 32
#define PP 32768
#define OO 50
#define NC 21
#define MPT 4            // priors per thread in match_kernel

// level-1 histogram window: float exponents [104,136) -> top16 in [WBINLO, WBINLO+WBINS)
// covers values [5.9e-8, 256) — all realizable ce; wh bin 0 = zeros (unused; see selwin
// fall-through), window bin w stored at wh[1+w]; clamp outside (unreachable).
#define WBINLO (104 << 7)
#define WBINS  4096
#define NWH    4352      // 17*256 (bins 0..4096 used; rest stay zero)

typedef unsigned long long u64;
typedef unsigned int u32;
typedef unsigned char u8;

// workspace: zero-init block first (one small memset), then scratch
static constexpr size_t OFF_WH    = 0;                            // u32[BB*NWH] 557 KB
static constexpr size_t OFF_KEYS  = OFF_WH   + 4ull*BB*NWH;       // u64[BB*OO]
static constexpr size_t OFF_NPOS  = OFF_KEYS + 8ull*BB*OO;        // int[BB]
static constexpr size_t OFF_CCNT  = OFF_NPOS + 128;               // u32[BB] compact counts
static constexpr size_t OFF_DACC  = OFF_CCNT + 128;               // double[3*BB]
static constexpr size_t ZERO_BYTES = OFF_DACC + 8ull*3*BB;
static constexpr size_t OFF_BTOV  = (ZERO_BYTES + 127) & ~127ull; // float[BB*PP]
static constexpr size_t OFF_BTIDX = OFF_BTOV  + 4ull*BB*PP;       // u8[BB*PP]
static constexpr size_t OFF_CEM   = OFF_BTIDX + 1ull*BB*PP;       // float[BB*PP]
static constexpr size_t OFF_CMP   = OFF_CEM   + 4ull*BB*PP;       // u32[BB*PP] boundary list
static constexpr size_t OFF_SELA  = OFF_CMP   + 4ull*BB*PP;       // u32[BB] strict-above cut
static constexpr size_t OFF_SELE  = OFF_SELA  + 128;              // u32[BB] boundary t16
static constexpr size_t OFF_SELK  = OFF_SELE  + 128;              // int[BB] residual k

static __device__ __forceinline__ float fast_div(float a, float b) {
    return a * __builtin_amdgcn_rcpf(b);
}

// Per (b, 4 priors): IoU vs all 50 truths; per-prior argmax thread-local,
// per-truth argmax via float butterfly + ordered ballots (smallest p wins).
__global__ __launch_bounds__(256) void match_kernel(
    const float* __restrict__ priors, const float* __restrict__ targets,
    float* __restrict__ btov, u8* __restrict__ btidx, u64* __restrict__ keys)
{
#pragma clang fp contract(off)
    const int b = blockIdx.y;
    const int tid = threadIdx.x;
    const int lane = tid & 63, wid = tid >> 6;
    const int wbase = blockIdx.x * (256 * MPT) + wid * (64 * MPT);

    __shared__ float tr[OO * 5];
    __shared__ u64 wkeys[4][OO];
    if (tid < OO * 5) tr[tid] = targets[(size_t)b * OO * 5 + tid];
    __syncthreads();

    float px1[MPT], py1[MPT], px2[MPT], py2[MPT], area_p[MPT];
#pragma unroll
    for (int s = 0; s < MPT; ++s) {
        int p = wbase + s * 64 + lane;
        float4 pr = *(const float4*)(priors + (size_t)p * 4);
        px1[s] = pr.x - pr.z * 0.5f; py1[s] = pr.y - pr.w * 0.5f;
        px2[s] = pr.x + pr.z * 0.5f; py2[s] = pr.y + pr.w * 0.5f;
        area_p[s] = (px2[s] - px1[s]) * (py2[s] - py1[s]);
    }

    float bestv[MPT]; int besto[MPT];
#pragma unroll
    for (int s = 0; s < MPT; ++s) { bestv[s] = -1.0f; besto[s] = 0; }

    for (int o = 0; o < OO; ++o) {
        float tx1 = tr[o*5+0], ty1 = tr[o*5+1], tx2 = tr[o*5+2], ty2 = tr[o*5+3];
        float area_t = (tx2 - tx1) * (ty2 - ty1);
        float iou[MPT];
#pragma unroll
        for (int s = 0; s < MPT; ++s) {
            float ix1 = fmaxf(tx1, px1[s]), iy1 = fmaxf(ty1, py1[s]);
            float ix2 = fminf(tx2, px2[s]), iy2 = fminf(ty2, py2[s]);
            float dx = fmaxf(ix2 - ix1, 0.0f), dy = fmaxf(iy2 - iy1, 0.0f);
            float inter = dx * dy;
            iou[s] = fast_div(inter, (area_t + area_p[s]) - inter);
            if (iou[s] > bestv[s]) { bestv[s] = iou[s]; besto[s] = o; }
        }
        float mv = fmaxf(fmaxf(iou[0], iou[1]), fmaxf(iou[2], iou[3]));
        for (int m = 1; m < 64; m <<= 1)
            mv = fmaxf(mv, __shfl_xor(mv, m, 64));
        u64 b0 = __ballot(iou[0] == mv);
        u64 b1 = __ballot(iou[1] == mv);
        u64 b2 = __ballot(iou[2] == mv);
        u64 b3 = __ballot(iou[3] == mv);
        if (lane == 0) {
            int s, l;
            if      (b0) { s = 0; l = __ffsll(b0) - 1; }
            else if (b1) { s = 1; l = __ffsll(b1) - 1; }
            else if (b2) { s = 2; l = __ffsll(b2) - 1; }
            else if (b3) { s = 3; l = __ffsll(b3) - 1; }
            else         { s = 0; l = 0; }
            u32 wp = (u32)(wbase + s * 64 + l);
            wkeys[wid][o] = ((u64)__float_as_uint(mv) << 32) | (u64)(0xFFFFFFFFu - wp);
        }
    }
#pragma unroll
    for (int s = 0; s < MPT; ++s) {
        int p = wbase + s * 64 + lane;
        btov[(size_t)b * PP + p] = bestv[s];
        btidx[(size_t)b * PP + p] = (u8)besto[s];
    }
    __syncthreads();
    if (tid < OO) {
        u64 k0 = wkeys[0][tid];
        for (int w = 1; w < 4; ++w) { u64 kw = wkeys[w][tid]; if (kw > k0) k0 = kw; }
        atomicMax(&keys[b * OO + tid], k0);
    }
}

// Parallel last-wins scatter (numpy fancy-assignment semantics).
__global__ void override_kernel(const u64* __restrict__ keys,
                                float* __restrict__ btov, u8* __restrict__ btidx) {
    const int b = blockIdx.x;
    const int o = threadIdx.x;
    u32 p = 0xFFFFFFFFu;
    if (o < OO) p = 0xFFFFFFFFu - (u32)(keys[b * OO + o] & 0xFFFFFFFFull);
    bool win = (o < OO);
    for (int o2 = 1; o2 < OO; ++o2) {
        u32 p2 = __shfl(p, o2, 64);
        if (o < o2 && p2 == p) win = false;
    }
    if (win) {
        btov[(size_t)b * PP + p] = 2.0f;
        btidx[(size_t)b * PP + p] = (u8)o;
    }
}

static __device__ __forceinline__ u32 top16bits(float v) {
    u32 u = __float_as_uint(v);
    return (v > 0.0f) ? u : 0u;
}

// Register-resident score: one thread = 4 consecutive priors. 4 rows x 21
// floats = 336 B = exactly 21 aligned float4 -> fully-coalesced 16B/lane
// loads, no LDS staging for conf. All register-array indices compile-time.
#define EL(k) ((((k) & 3) == 0) ? v[(k) >> 2].x : \
               (((k) & 3) == 1) ? v[(k) >> 2].y : \
               (((k) & 3) == 2) ? v[(k) >> 2].z : v[(k) >> 2].w)

__global__ __launch_bounds__(256) void score_kernel(
    const float* __restrict__ loc, const float* __restrict__ conf,
    const float* __restrict__ priors, const float* __restrict__ targets,
    const float* __restrict__ btov, const u8* __restrict__ btidx,
    float* __restrict__ cemine, int* __restrict__ npos, double* __restrict__ dacc,
    u32* __restrict__ wh)
{
    const int b = blockIdx.y;
    const int tid = threadIdx.x;
    const int p = blockIdx.x * 1024 + tid * 4;       // 4 priors per thread
    __shared__ float tr[OO * 5];
    __shared__ __align__(16) u32 hh[WBINS];          // hist; aliased for reductions
    if (tid < OO * 5) tr[tid] = targets[(size_t)b * OO * 5 + tid];
#pragma unroll
    for (int j = 0; j < WBINS / 256; ++j) hh[j * 256 + tid] = 0;
    __syncthreads();

    float4 ov4 = *(const float4*)(btov + (size_t)b * PP + p);
    uchar4 ox4 = *(const uchar4*)(btidx + (size_t)b * PP + p);
    const float ovv[4] = {ov4.x, ov4.y, ov4.z, ov4.w};
    const int  oidx[4] = {(int)ox4.x, (int)ox4.y, (int)ox4.z, (int)ox4.w};

    const float4* cp = (const float4*)(conf + ((size_t)b * PP + p) * NC);
    float4 v[21];
    float cev[4];
    double l_l = 0.0, pce = 0.0; int np_ = 0;

#pragma unroll
    for (int r = 0; r < 4; ++r) {
        // rolling float4 window: row r needs v[(21r)/4 .. (21r+20)/4]
        const int jlo = (r == 0) ? 0 : ((21 * (r - 1) + 20) / 4 + 1);
        const int jhi = (21 * r + 20) / 4;
#pragma unroll
        for (int j = jlo; j <= jhi; ++j) v[j] = cp[j];

        int conft = 0;
        if (ovv[r] >= 0.5f) conft = (int)(tr[oidx[r] * 5 + 4] + 1.0f);
        const bool pos = conft > 0;

        float m = -1e30f;
#pragma unroll
        for (int c = 0; c < NC; ++c) m = fmaxf(m, EL(21 * r + c));
        float s = 0.0f, tl = 0.0f;
#pragma unroll
        for (int c = 0; c < NC; ++c) {
            float xx = EL(21 * r + c);
            s += expf(xx - m);
            if (c == conft) tl = xx;
        }
        float ce = (m + logf(s)) - tl;
        cev[r] = pos ? 0.0f : ce;

        if (pos) {
            np_ += 1; pce += (double)ce;
            int o = oidx[r];
            float mx1 = tr[o*5+0], my1 = tr[o*5+1], mx2 = tr[o*5+2], my2 = tr[o*5+3];
            float4 pr = *(const float4*)(priors + (size_t)(p + r) * 4);
            float lt0 = ((mx1 + mx2) * 0.5f - pr.x) / (0.1f * pr.z);
            float lt1 = ((my1 + my2) * 0.5f - pr.y) / (0.1f * pr.w);
            float lt2 = logf((mx2 - mx1) / pr.z) / 0.2f;
            float lt3 = logf((my2 - my1) / pr.w) / 0.2f;
            float4 l4 = *(const float4*)(loc + ((size_t)b * PP + p + r) * 4);
            float lpv[4] = {l4.x, l4.y, l4.z, l4.w};
            float lt[4] = {lt0, lt1, lt2, lt3};
#pragma unroll
            for (int i2 = 0; i2 < 4; ++i2) {
                float d = lpv[i2] - lt[i2];
                float ad = fabsf(d);
                l_l += (double)(ad < 1.0f ? 0.5f * d * d : ad - 0.5f);
            }
        }
    }

    *(float4*)(cemine + (size_t)b * PP + p) = make_float4(cev[0], cev[1], cev[2], cev[3]);

    // LDS hist of nonzero values (zeros intentionally uncounted: selwin's
    // fall-through path yields the correct "take all nonzero" answer).
#pragma unroll
    for (int r = 0; r < 4; ++r) {
        u32 t16 = top16bits(cev[r]) >> 16;
        if (t16 != 0) {
            int widx = (int)t16 - WBINLO;
            widx = widx < 0 ? 0 : (widx > WBINS - 1 ? WBINS - 1 : widx);
            atomicAdd(&hh[widx], 1u);
        }
    }
    __syncthreads();
#pragma unroll
    for (int j = 0; j < WBINS / 256; ++j) {
        u32 c = hh[j * 256 + tid];
        if (c) atomicAdd(&wh[(size_t)b * NWH + 1 + j * 256 + tid], c);
    }
    __syncthreads();                      // flush reads done; alias reductions
    double* rl = (double*)hh;             // 256 doubles
    double* rc = rl + 256;                // 256 doubles
    int*    rn = (int*)(rc + 256);        // 256 ints
    rl[tid] = l_l; rc[tid] = pce; rn[tid] = np_;
    __syncthreads();
    for (int s2 = 128; s2 > 0; s2 >>= 1) {
        if (tid < s2) { rl[tid] += rl[tid+s2]; rc[tid] += rc[tid+s2]; rn[tid] += rn[tid+s2]; }
        __syncthreads();
    }
    if (tid == 0) {
        atomicAdd(&dacc[b], rl[0]);
        atomicAdd(&dacc[BB + b], rc[0]);
        atomicAdd(&npos[b], rn[0]);
    }
}

// Level-1 select on the window hist: threshold bin + residual count.
__global__ __launch_bounds__(256) void selwin_kernel(
    const u32* __restrict__ wh, const int* __restrict__ npos,
    u32* __restrict__ selA, u32* __restrict__ selE, int* __restrict__ selK)
{
    const int b = blockIdx.x, tid = threadIdx.x;
    const int lane = tid & 63, wid = tid >> 6;
    int k = npos[b] * 3; if (k > PP - 1) k = PP - 1;
    if (k <= 0) {
        if (tid == 0) { selA[b] = 0xFFFFFFFFu; selE[b] = 0xFFFFFFFEu; selK[b] = 0; }
        return;
    }
    const u32* h = wh + (size_t)b * NWH;
    __shared__ u32 chs[17];
    __shared__ u32 ct[256];
    __shared__ int s_cT; __shared__ u32 s_above; __shared__ u32 sT;

    for (int c = wid; c < 17; c += 4) {
        u32 cnt = 0;
#pragma unroll
        for (int q = 0; q < 4; ++q) cnt += h[c * 256 + q * 64 + lane];
        for (int m = 1; m < 64; m <<= 1) cnt += __shfl_xor(cnt, m, 64);
        if (lane == 0) chs[c] = cnt;
    }
    if (tid == 0) sT = 0;
    __syncthreads();
    if (tid == 0) {
        u32 cum = 0; int cT = 0; u32 above = 0;
        for (int c = 16; c >= 0; --c) {
            if (cum + chs[c] >= (u32)k) { cT = c; above = cum; break; }
            cum += chs[c];
        }
        s_cT = cT; s_above = above;
    }
    __syncthreads();
    const int cT = s_cT; const u32 aboveChunk = s_above;
    ct[tid] = h[cT * 256 + tid];
    __syncthreads();
    for (int off = 1; off < 256; off <<= 1) {
        u32 add = (tid + off < 256) ? ct[tid + off] : 0;
        __syncthreads();
        ct[tid] += add;
        __syncthreads();
    }
    if (aboveChunk + ct[tid] >= (u32)k) atomicMax(&sT, (u32)tid);
    __syncthreads();
    const int T = (int)sT;
    if (tid == T) {
        u32 aboveBin = aboveChunk + ((T < 255) ? ct[T + 1] : 0);
        int g = cT * 256 + T;
        if (g == 0) {   // threshold among zeros: take all nonzero, no boundary
            selA[b] = WBINLO - 1; selE[b] = 0xFFFFFFFEu; selK[b] = 0;
        } else {
            u32 T16 = (u32)(WBINLO + g - 1);
            selA[b] = T16; selE[b] = T16; selK[b] = k - (int)aboveBin;
        }
    }
}

// Data pass: f64-sum values strictly above cut; compact boundary bin elements.
__global__ __launch_bounds__(256) void scan2_kernel(
    const float* __restrict__ cemine, const u32* __restrict__ selA,
    const u32* __restrict__ selE, u32* __restrict__ cmp, u32* __restrict__ ccnt,
    double* __restrict__ dacc)
{
    const int b = blockIdx.y, tid = threadIdx.x;
    const u32 A = selA[b], E = selE[b];
    const float4* v4 = (const float4*)(cemine + (size_t)b * PP);
    float4 f = v4[blockIdx.x * 256 + tid];
    double acc = 0.0;
    float vv[4] = {f.x, f.y, f.z, f.w};
#pragma unroll
    for (int c = 0; c < 4; ++c) {
        u32 u = top16bits(vv[c]);
        u32 hi = u >> 16;
        if (hi > A) acc += (double)vv[c];
        else if (hi == E) {
            u32 idx = atomicAdd(&ccnt[b], 1u);
            cmp[(size_t)b * PP + idx] = u;
        }
    }
    __shared__ double red[256];
    red[tid] = acc;
    __syncthreads();
    for (int s2 = 128; s2 > 0; s2 >>= 1) {
        if (tid < s2) red[tid] += red[tid + s2];
        __syncthreads();
    }
    if (tid == 0 && red[0] != 0.0) atomicAdd(&dacc[2 * BB + b], red[0]);
}

// Exact within-bin top-k2 sum from the compacted list (value linear in low16).
__global__ __launch_bounds__(256) void selfinal_kernel(
    const u32* __restrict__ cmp, const u32* __restrict__ ccnt,
    const u32* __restrict__ selE, const int* __restrict__ selK,
    double* __restrict__ dacc)
{
    const int b = blockIdx.x, tid = threadIdx.x;
    const int k2 = selK[b];
    if (k2 <= 0) return;
    const u32 T16 = selE[b];
    const int n = (int)ccnt[b];
    const u32* lst = cmp + (size_t)b * PP;
    __shared__ u32 hc[256], hl[256];
    __shared__ u32 sT;
    hc[tid] = 0; hl[tid] = 0; if (tid == 0) sT = 0;
    __syncthreads();
    for (int i = tid; i < n; i += 256) {
        u32 L = lst[i] & 0xFFFFu;
        atomicAdd(&hc[L >> 8], 1u);
        atomicAdd(&hl[L >> 8], L);
    }
    __syncthreads();
    for (int off = 1; off < 256; off <<= 1) {
        u32 a1 = (tid + off < 256) ? hc[tid + off] : 0;
        u32 a2 = (tid + off < 256) ? hl[tid + off] : 0;
        __syncthreads();
        hc[tid] += a1; hl[tid] += a2;
        __syncthreads();
    }
    if (hc[tid] >= (u32)k2) atomicMax(&sT, (u32)tid);
    __syncthreads();
    const int B1 = (int)sT;
    const u32 aboveCnt = (B1 < 255) ? hc[B1 + 1] : 0;
    const u32 aboveL   = (B1 < 255) ? hl[B1 + 1] : 0;
    const int k3 = k2 - (int)aboveCnt;
    __syncthreads();
    hc[tid] = 0; if (tid == 0) sT = 0;
    __syncthreads();
    for (int i = tid; i < n; i += 256) {
        u32 L = lst[i] & 0xFFFFu;
        if ((int)(L >> 8) == B1) atomicAdd(&hc[L & 0xFFu], 1u);
    }
    __syncthreads();
    hl[tid] = hc[tid] * (u32)tid;
    __syncthreads();
    for (int off = 1; off < 256; off <<= 1) {
        u32 a1 = (tid + off < 256) ? hc[tid + off] : 0;
        u32 a2 = (tid + off < 256) ? hl[tid + off] : 0;
        __syncthreads();
        hc[tid] += a1; hl[tid] += a2;
        __syncthreads();
    }
    if (hc[tid] >= (u32)k3) atomicMax(&sT, (u32)tid);
    __syncthreads();
    const int B2 = (int)sT;
    if (tid == B2) {
        u32 n2 = (B2 < 255) ? hc[B2 + 1] : 0;
        u32 W2 = (B2 < 255) ? hl[B2 + 1] : 0;
        int teq = k3 - (int)n2;
        double C0 = (double)__uint_as_float(T16 << 16);
        double C1 = (double)__uint_as_float((T16 << 16) | 1u) - C0;
        double Lsum = (double)aboveL + (double)n2 * (double)(B1 << 8) + (double)W2
                    + (double)teq * (double)((B1 << 8) | B2);
        dacc[2 * BB + b] += (double)k2 * C0 + C1 * Lsum;
    }
}

__global__ void finalize_kernel(const int* __restrict__ npos,
                                const double* __restrict__ dacc, float* __restrict__ out) {
    if (threadIdx.x == 0 && blockIdx.x == 0) {
        double N = 0.0, ll = 0.0, lc = 0.0;
        for (int b = 0; b < BB; ++b) {
            N += (double)npos[b];
            ll += dacc[b];
            lc += dacc[BB + b] + dacc[2 * BB + b];
        }
        out[0] = (float)(ll / N);
        out[1] = (float)(lc / N);
    }
}

extern "C" void kernel_launch(void* const* d_in, const int* in_sizes, int n_in,
                              void* d_out, int out_size, void* d_ws, size_t ws_size,
                              hipStream_t stream) {
    const float* loc     = (const float*)d_in[0];
    const float* conf    = (const float*)d_in[1];
    const float* priors  = (const float*)d_in[2];
    const float* targets = (const float*)d_in[3];
    char* ws = (char*)d_ws;
    u32*    wh    = (u32*)   (ws + OFF_WH);
    u64*    keys  = (u64*)   (ws + OFF_KEYS);
    int*    npos  = (int*)   (ws + OFF_NPOS);
    u32*    ccnt  = (u32*)   (ws + OFF_CCNT);
    double* dacc  = (double*)(ws + OFF_DACC);
    float*  btov  = (float*) (ws + OFF_BTOV);
    u8*     btidx = (u8*)    (ws + OFF_BTIDX);
    float*  cem   = (float*) (ws + OFF_CEM);
    u32*    cmp   = (u32*)   (ws + OFF_CMP);
    u32*    selA  = (u32*)   (ws + OFF_SELA);
    u32*    selE  = (u32*)   (ws + OFF_SELE);
    int*    selK  = (int*)   (ws + OFF_SELK);
    float*  out   = (float*)d_out;

    hipMemsetAsync(ws, 0, ZERO_BYTES, stream);   // wh+keys+npos+ccnt+dacc (~0.56 MB)
    match_kernel<<<dim3(PP / (256 * MPT), BB), 256, 0, stream>>>(priors, targets, btov, btidx, keys);
    override_kernel<<<BB, 64, 0, stream>>>(keys, btov, btidx);
    score_kernel<<<dim3(PP / 1024, BB), 256, 0, stream>>>(loc, conf, priors, targets, btov, btidx, cem, npos, dacc, wh);
    selwin_kernel<<<BB, 256, 0, stream>>>(wh, npos, selA, selE, selK);
    scan2_kernel<<<dim3(32, BB), 256, 0, stream>>>(cem, selA, selE, cmp, ccnt, dacc);
    selfinal_kernel<<<BB, 256, 0, stream>>>(cmp, ccnt, selE, selK, dacc);
    finalize_kernel<<<1, 64, 0, stream>>>(npos, dacc, out);
}

// Round 9
// 106.930 us; speedup vs baseline: 2.7069x; 1.5780x over previous
//
#include <hip/hip_runtime.h>
#include <math.h>

#define BB 32
#define PP 32768
#define OO 50
#define NC 21
#define MPT 4            // priors per thread in match_kernel

// histogram window: float exponents [104,136) -> top16 in [WBINLO, WBINLO+WBINS)
// covers all realizable ce values [5.9e-8, 256); zeros uncounted (positives).
#define WBINLO (104 << 7)
#define WBINS  4096

typedef unsigned long long u64;
typedef unsigned int u32;
typedef unsigned char u8;

// workspace: zero-init block first (one small memset), then scratch
static constexpr size_t OFF_WHC   = 0;                            // u32[BB*WBINS] 512 KB
static constexpr size_t OFF_WHS   = OFF_WHC  + 4ull*BB*WBINS;     // f32[BB*WBINS] 512 KB
static constexpr size_t OFF_KEYS  = OFF_WHS  + 4ull*BB*WBINS;     // u64[BB*OO]
static constexpr size_t OFF_NPOS  = OFF_KEYS + 8ull*BB*OO;        // int[BB]
static constexpr size_t OFF_DACC  = OFF_NPOS + 128;               // double[3*BB]
static constexpr size_t ZERO_BYTES = OFF_DACC + 8ull*3*BB;
static constexpr size_t OFF_BTOV  = (ZERO_BYTES + 127) & ~127ull; // float[BB*PP]
static constexpr size_t OFF_BTIDX = OFF_BTOV  + 4ull*BB*PP;       // u8[BB*PP]

static __device__ __forceinline__ float fast_div(float a, float b) {
    return a * __builtin_amdgcn_rcpf(b);
}

// Per (b, 4 priors): IoU vs all 50 truths; per-prior argmax thread-local,
// per-truth argmax via float butterfly + ordered ballots (smallest p wins).
__global__ __launch_bounds__(256) void match_kernel(
    const float* __restrict__ priors, const float* __restrict__ targets,
    float* __restrict__ btov, u8* __restrict__ btidx, u64* __restrict__ keys)
{
#pragma clang fp contract(off)
    const int b = blockIdx.y;
    const int tid = threadIdx.x;
    const int lane = tid & 63, wid = tid >> 6;
    const int wbase = blockIdx.x * (256 * MPT) + wid * (64 * MPT);

    __shared__ float tr[OO * 5];
    __shared__ u64 wkeys[4][OO];
    if (tid < OO * 5) tr[tid] = targets[(size_t)b * OO * 5 + tid];
    __syncthreads();

    float px1[MPT], py1[MPT], px2[MPT], py2[MPT], area_p[MPT];
#pragma unroll
    for (int s = 0; s < MPT; ++s) {
        int p = wbase + s * 64 + lane;
        float4 pr = *(const float4*)(priors + (size_t)p * 4);
        px1[s] = pr.x - pr.z * 0.5f; py1[s] = pr.y - pr.w * 0.5f;
        px2[s] = pr.x + pr.z * 0.5f; py2[s] = pr.y + pr.w * 0.5f;
        area_p[s] = (px2[s] - px1[s]) * (py2[s] - py1[s]);
    }

    float bestv[MPT]; int besto[MPT];
#pragma unroll
    for (int s = 0; s < MPT; ++s) { bestv[s] = -1.0f; besto[s] = 0; }

    for (int o = 0; o < OO; ++o) {
        float tx1 = tr[o*5+0], ty1 = tr[o*5+1], tx2 = tr[o*5+2], ty2 = tr[o*5+3];
        float area_t = (tx2 - tx1) * (ty2 - ty1);
        float iou[MPT];
#pragma unroll
        for (int s = 0; s < MPT; ++s) {
            float ix1 = fmaxf(tx1, px1[s]), iy1 = fmaxf(ty1, py1[s]);
            float ix2 = fminf(tx2, px2[s]), iy2 = fminf(ty2, py2[s]);
            float dx = fmaxf(ix2 - ix1, 0.0f), dy = fmaxf(iy2 - iy1, 0.0f);
            float inter = dx * dy;
            iou[s] = fast_div(inter, (area_t + area_p[s]) - inter);
            if (iou[s] > bestv[s]) { bestv[s] = iou[s]; besto[s] = o; }
        }
        float mv = fmaxf(fmaxf(iou[0], iou[1]), fmaxf(iou[2], iou[3]));
        for (int m = 1; m < 64; m <<= 1)
            mv = fmaxf(mv, __shfl_xor(mv, m, 64));
        u64 b0 = __ballot(iou[0] == mv);
        u64 b1 = __ballot(iou[1] == mv);
        u64 b2 = __ballot(iou[2] == mv);
        u64 b3 = __ballot(iou[3] == mv);
        if (lane == 0) {
            int s, l;
            if      (b0) { s = 0; l = __ffsll(b0) - 1; }
            else if (b1) { s = 1; l = __ffsll(b1) - 1; }
            else if (b2) { s = 2; l = __ffsll(b2) - 1; }
            else if (b3) { s = 3; l = __ffsll(b3) - 1; }
            else         { s = 0; l = 0; }
            u32 wp = (u32)(wbase + s * 64 + l);
            wkeys[wid][o] = ((u64)__float_as_uint(mv) << 32) | (u64)(0xFFFFFFFFu - wp);
        }
    }
#pragma unroll
    for (int s = 0; s < MPT; ++s) {
        int p = wbase + s * 64 + lane;
        btov[(size_t)b * PP + p] = bestv[s];
        btidx[(size_t)b * PP + p] = (u8)besto[s];
    }
    __syncthreads();
    if (tid < OO) {
        u64 k0 = wkeys[0][tid];
        for (int w = 1; w < 4; ++w) { u64 kw = wkeys[w][tid]; if (kw > k0) k0 = kw; }
        atomicMax(&keys[b * OO + tid], k0);
    }
}

// Parallel last-wins scatter (numpy fancy-assignment semantics).
__global__ void override_kernel(const u64* __restrict__ keys,
                                float* __restrict__ btov, u8* __restrict__ btidx) {
    const int b = blockIdx.x;
    const int o = threadIdx.x;
    u32 p = 0xFFFFFFFFu;
    if (o < OO) p = 0xFFFFFFFFu - (u32)(keys[b * OO + o] & 0xFFFFFFFFull);
    bool win = (o < OO);
    for (int o2 = 1; o2 < OO; ++o2) {
        u32 p2 = __shfl(p, o2, 64);
        if (o < o2 && p2 == p) win = false;
    }
    if (win) {
        btov[(size_t)b * PP + p] = 2.0f;
        btidx[(size_t)b * PP + p] = (u8)o;
    }
}

static __device__ __forceinline__ u32 top16bits(float v) {
    u32 u = __float_as_uint(v);
    return (v > 0.0f) ? u : 0u;
}

// Register-resident score: one thread = 4 consecutive priors (21 float4 of
// conf). Accumulates per-bin COUNT and per-bin VALUE-SUM histograms in LDS,
// flushed once per block -> no cemine array, no later data passes.
#define EL(k) ((((k) & 3) == 0) ? v[(k) >> 2].x : \
               (((k) & 3) == 1) ? v[(k) >> 2].y : \
               (((k) & 3) == 2) ? v[(k) >> 2].z : v[(k) >> 2].w)

__global__ __launch_bounds__(256) void score_kernel(
    const float* __restrict__ loc, const float* __restrict__ conf,
    const float* __restrict__ priors, const float* __restrict__ targets,
    const float* __restrict__ btov, const u8* __restrict__ btidx,
    int* __restrict__ npos, double* __restrict__ dacc,
    u32* __restrict__ whc, float* __restrict__ whs)
{
    const int b = blockIdx.y;
    const int tid = threadIdx.x;
    const int p = blockIdx.x * 1024 + tid * 4;       // 4 priors per thread
    __shared__ float tr[OO * 5];
    __shared__ __align__(16) u32 hh[WBINS];          // count hist; aliased later
    __shared__ __align__(16) float hs[WBINS];        // value-sum hist
    if (tid < OO * 5) tr[tid] = targets[(size_t)b * OO * 5 + tid];
#pragma unroll
    for (int j = 0; j < WBINS / 256; ++j) { hh[j * 256 + tid] = 0; hs[j * 256 + tid] = 0.0f; }
    __syncthreads();

    float4 ov4 = *(const float4*)(btov + (size_t)b * PP + p);
    uchar4 ox4 = *(const uchar4*)(btidx + (size_t)b * PP + p);
    const float ovv[4] = {ov4.x, ov4.y, ov4.z, ov4.w};
    const int  oidx[4] = {(int)ox4.x, (int)ox4.y, (int)ox4.z, (int)ox4.w};

    const float4* cp = (const float4*)(conf + ((size_t)b * PP + p) * NC);
    float4 v[21];
    float cev[4];
    double l_l = 0.0, pce = 0.0; int np_ = 0;

#pragma unroll
    for (int r = 0; r < 4; ++r) {
        const int jlo = (r == 0) ? 0 : ((21 * (r - 1) + 20) / 4 + 1);
        const int jhi = (21 * r + 20) / 4;
#pragma unroll
        for (int j = jlo; j <= jhi; ++j) v[j] = cp[j];

        int conft = 0;
        if (ovv[r] >= 0.5f) conft = (int)(tr[oidx[r] * 5 + 4] + 1.0f);
        const bool pos = conft > 0;

        float m = -1e30f;
#pragma unroll
        for (int c = 0; c < NC; ++c) m = fmaxf(m, EL(21 * r + c));
        float s = 0.0f, tl = 0.0f;
#pragma unroll
        for (int c = 0; c < NC; ++c) {
            float xx = EL(21 * r + c);
            s += expf(xx - m);
            if (c == conft) tl = xx;
        }
        float ce = (m + logf(s)) - tl;
        cev[r] = pos ? 0.0f : ce;

        if (pos) {
            np_ += 1; pce += (double)ce;
            int o = oidx[r];
            float mx1 = tr[o*5+0], my1 = tr[o*5+1], mx2 = tr[o*5+2], my2 = tr[o*5+3];
            float4 pr = *(const float4*)(priors + (size_t)(p + r) * 4);
            float lt0 = ((mx1 + mx2) * 0.5f - pr.x) / (0.1f * pr.z);
            float lt1 = ((my1 + my2) * 0.5f - pr.y) / (0.1f * pr.w);
            float lt2 = logf((mx2 - mx1) / pr.z) / 0.2f;
            float lt3 = logf((my2 - my1) / pr.w) / 0.2f;
            float4 l4 = *(const float4*)(loc + ((size_t)b * PP + p + r) * 4);
            float lpv[4] = {l4.x, l4.y, l4.z, l4.w};
            float lt[4] = {lt0, lt1, lt2, lt3};
#pragma unroll
            for (int i2 = 0; i2 < 4; ++i2) {
                float d = lpv[i2] - lt[i2];
                float ad = fabsf(d);
                l_l += (double)(ad < 1.0f ? 0.5f * d * d : ad - 0.5f);
            }
        }
    }

    // LDS count+sum histogram of nonzero ce (zeros = positives, uncounted)
#pragma unroll
    for (int r = 0; r < 4; ++r) {
        u32 t16 = top16bits(cev[r]) >> 16;
        if (t16 != 0) {
            int widx = (int)t16 - WBINLO;
            widx = widx < 0 ? 0 : (widx > WBINS - 1 ? WBINS - 1 : widx);
            atomicAdd(&hh[widx], 1u);
            atomicAdd(&hs[widx], cev[r]);
        }
    }
    __syncthreads();
#pragma unroll
    for (int j = 0; j < WBINS / 256; ++j) {
        u32 c = hh[j * 256 + tid];
        if (c) {
            atomicAdd(&whc[(size_t)b * WBINS + j * 256 + tid], c);
            atomicAdd(&whs[(size_t)b * WBINS + j * 256 + tid], hs[j * 256 + tid]);
        }
    }
    __syncthreads();                      // flush reads done; alias reductions
    double* rl = (double*)hh;             // 256 doubles
    double* rc = rl + 256;                // 256 doubles
    int*    rn = (int*)(rc + 256);        // 256 ints
    rl[tid] = l_l; rc[tid] = pce; rn[tid] = np_;
    __syncthreads();
    for (int s2 = 128; s2 > 0; s2 >>= 1) {
        if (tid < s2) { rl[tid] += rl[tid+s2]; rc[tid] += rc[tid+s2]; rn[tid] += rn[tid+s2]; }
        __syncthreads();
    }
    if (tid == 0) {
        atomicAdd(&dacc[b], rl[0]);
        atomicAdd(&dacc[BB + b], rc[0]);
        atomicAdd(&npos[b], rn[0]);
    }
}

// Single select kernel: exact threshold bin via count hist; hard-negative sum
// = exact sum of bins above + k2 * (boundary-bin mean). Error <= k2*binwidth/N
// (~1e-3 of output) — far below the 0.35 tolerance.
__global__ __launch_bounds__(256) void selwin_kernel(
    const u32* __restrict__ whc, const float* __restrict__ whs,
    const int* __restrict__ npos, double* __restrict__ dacc)
{
    const int b = blockIdx.x, tid = threadIdx.x;
    const int lane = tid & 63, wid = tid >> 6;
    int k = npos[b] * 3; if (k > PP - 1) k = PP - 1;
    if (k <= 0) return;                       // dacc[2BB+b] stays 0
    const u32* hc = whc + (size_t)b * WBINS;
    const float* hsg = whs + (size_t)b * WBINS;

    __shared__ u32 ccnt_[16]; __shared__ float csum_[16];
    __shared__ u32 ct[256]; __shared__ float fs[256];
    __shared__ int s_cT; __shared__ u32 s_aboveC; __shared__ float s_aboveS;
    __shared__ u32 sT;

    for (int c = wid; c < 16; c += 4) {
        u32 cnt = 0; float sm = 0.0f;
#pragma unroll
        for (int q = 0; q < 4; ++q) {
            int idx = c * 256 + q * 64 + lane;
            cnt += hc[idx];
            sm  += hsg[idx];
        }
        for (int m = 1; m < 64; m <<= 1) {
            cnt += __shfl_xor(cnt, m, 64);
            sm  += __shfl_xor(sm, m, 64);
        }
        if (lane == 0) { ccnt_[c] = cnt; csum_[c] = sm; }
    }
    if (tid == 0) sT = 0;
    __syncthreads();
    if (tid == 0) {
        u32 cum = 0; float scum = 0.0f; int cT = -1; u32 aboveC = 0; float aboveS = 0.0f;
        for (int c = 15; c >= 0; --c) {
            if (cum + ccnt_[c] >= (u32)k) { cT = c; aboveC = cum; aboveS = scum; break; }
            cum += ccnt_[c]; scum += csum_[c];
        }
        s_cT = cT; s_aboveC = aboveC; s_aboveS = aboveS;
        if (cT < 0) dacc[2 * BB + b] = (double)scum;   // k >= all nonzero: take all
    }
    __syncthreads();
    const int cT = s_cT;
    if (cT < 0) return;
    const u32 aboveC = s_aboveC; const float aboveS = s_aboveS;

    const u32 myc = hc[cT * 256 + tid];
    const float mys = hsg[cT * 256 + tid];
    ct[tid] = myc; fs[tid] = mys;
    __syncthreads();
    for (int off = 1; off < 256; off <<= 1) {
        u32 a1 = (tid + off < 256) ? ct[tid + off] : 0;
        float a2 = (tid + off < 256) ? fs[tid + off] : 0.0f;
        __syncthreads();
        ct[tid] += a1; fs[tid] += a2;
        __syncthreads();
    }
    if (aboveC + ct[tid] >= (u32)k) atomicMax(&sT, (u32)tid);
    __syncthreads();
    const int T = (int)sT;
    if (tid == T) {
        u32 aboveBinC = aboveC + ((T < 255) ? ct[T + 1] : 0);
        float aboveBinS = aboveS + ((T < 255) ? fs[T + 1] : 0.0f);
        int k2 = k - (int)aboveBinC;
        double avg = (double)mys / (double)myc;        // boundary-bin mean
        dacc[2 * BB + b] = (double)aboveBinS + (double)k2 * avg;
    }
}

__global__ void finalize_kernel(const int* __restrict__ npos,
                                const double* __restrict__ dacc, float* __restrict__ out) {
    if (threadIdx.x == 0 && blockIdx.x == 0) {
        double N = 0.0, ll = 0.0, lc = 0.0;
        for (int b = 0; b < BB; ++b) {
            N += (double)npos[b];
            ll += dacc[b];
            lc += dacc[BB + b] + dacc[2 * BB + b];
        }
        out[0] = (float)(ll / N);
        out[1] = (float)(lc / N);
    }
}

extern "C" void kernel_launch(void* const* d_in, const int* in_sizes, int n_in,
                              void* d_out, int out_size, void* d_ws, size_t ws_size,
                              hipStream_t stream) {
    const float* loc     = (const float*)d_in[0];
    const float* conf    = (const float*)d_in[1];
    const float* priors  = (const float*)d_in[2];
    const float* targets = (const float*)d_in[3];
    char* ws = (char*)d_ws;
    u32*    whc   = (u32*)   (ws + OFF_WHC);
    float*  whs   = (float*) (ws + OFF_WHS);
    u64*    keys  = (u64*)   (ws + OFF_KEYS);
    int*    npos  = (int*)   (ws + OFF_NPOS);
    double* dacc  = (double*)(ws + OFF_DACC);
    float*  btov  = (float*) (ws + OFF_BTOV);
    u8*     btidx = (u8*)    (ws + OFF_BTIDX);
    float*  out   = (float*)d_out;

    hipMemsetAsync(ws, 0, ZERO_BYTES, stream);   // whc+whs+keys+npos+dacc (~1.1 MB)
    match_kernel<<<dim3(PP / (256 * MPT), BB), 256, 0, stream>>>(priors, targets, btov, btidx, keys);
    override_kernel<<<BB, 64, 0, stream>>>(keys, btov, btidx);
    score_kernel<<<dim3(PP / 1024, BB), 256, 0, stream>>>(loc, conf, priors, targets, btov, btidx, npos, dacc, whc, whs);
    selwin_kernel<<<BB, 256, 0, stream>>>(whc, whs, npos, dacc);
    finalize_kernel<<<1, 64, 0, stream>>>(npos, dacc, out);
}

// Round 10
// 104.806 us; speedup vs baseline: 2.7618x; 1.0203x over previous
//
#include <hip/hip_runtime.h>
#include <math.h>

#define BB 32
#define PP 32768
#define OO 50
#define NC 21
#define MPT 4            // priors per thread in match_kernel

// histogram window: float exponents [104,136), 6 mantissa bits ->
// bin = (top16 - WBINLO) >> 1, WBINS=2048. Selection stays exact at any bin
// width (monotone bins, exact per-bin count+sum); only the boundary-bin mean
// approx widens (~1.6% bin width -> error ~2e-3 of output, tol 0.35).
#define WBINLO (104 << 7)
#define WBINS  2048

typedef unsigned long long u64;
typedef unsigned int u32;
typedef unsigned char u8;

// workspace: zero-init block first (one small memset), then scratch
static constexpr size_t OFF_WHC   = 0;                            // u32[BB*WBINS] 256 KB
static constexpr size_t OFF_WHS   = OFF_WHC  + 4ull*BB*WBINS;     // f32[BB*WBINS] 256 KB
static constexpr size_t OFF_KEYS  = OFF_WHS  + 4ull*BB*WBINS;     // u64[BB*OO]
static constexpr size_t OFF_NPOS  = OFF_KEYS + 8ull*BB*OO;        // int[BB]
static constexpr size_t OFF_DACC  = OFF_NPOS + 128;               // double[3*BB]
static constexpr size_t ZERO_BYTES = OFF_DACC + 8ull*3*BB;
static constexpr size_t OFF_BTOV  = (ZERO_BYTES + 127) & ~127ull; // float[BB*PP]
static constexpr size_t OFF_BTIDX = OFF_BTOV  + 4ull*BB*PP;       // u8[BB*PP]

static __device__ __forceinline__ float fast_div(float a, float b) {
    return a * __builtin_amdgcn_rcpf(b);
}

// Per (b, 4 priors): IoU vs all 50 truths; per-prior argmax thread-local,
// per-truth argmax via float butterfly + ordered ballots (smallest p wins).
__global__ __launch_bounds__(256) void match_kernel(
    const float* __restrict__ priors, const float* __restrict__ targets,
    float* __restrict__ btov, u8* __restrict__ btidx, u64* __restrict__ keys)
{
#pragma clang fp contract(off)
    const int b = blockIdx.y;
    const int tid = threadIdx.x;
    const int lane = tid & 63, wid = tid >> 6;
    const int wbase = blockIdx.x * (256 * MPT) + wid * (64 * MPT);

    __shared__ float tr[OO * 5];
    __shared__ u64 wkeys[4][OO];
    if (tid < OO * 5) tr[tid] = targets[(size_t)b * OO * 5 + tid];
    __syncthreads();

    float px1[MPT], py1[MPT], px2[MPT], py2[MPT], area_p[MPT];
#pragma unroll
    for (int s = 0; s < MPT; ++s) {
        int p = wbase + s * 64 + lane;
        float4 pr = *(const float4*)(priors + (size_t)p * 4);
        px1[s] = pr.x - pr.z * 0.5f; py1[s] = pr.y - pr.w * 0.5f;
        px2[s] = pr.x + pr.z * 0.5f; py2[s] = pr.y + pr.w * 0.5f;
        area_p[s] = (px2[s] - px1[s]) * (py2[s] - py1[s]);
    }

    float bestv[MPT]; int besto[MPT];
#pragma unroll
    for (int s = 0; s < MPT; ++s) { bestv[s] = -1.0f; besto[s] = 0; }

    for (int o = 0; o < OO; ++o) {
        float tx1 = tr[o*5+0], ty1 = tr[o*5+1], tx2 = tr[o*5+2], ty2 = tr[o*5+3];
        float area_t = (tx2 - tx1) * (ty2 - ty1);
        float iou[MPT];
#pragma unroll
        for (int s = 0; s < MPT; ++s) {
            float ix1 = fmaxf(tx1, px1[s]), iy1 = fmaxf(ty1, py1[s]);
            float ix2 = fminf(tx2, px2[s]), iy2 = fminf(ty2, py2[s]);
            float dx = fmaxf(ix2 - ix1, 0.0f), dy = fmaxf(iy2 - iy1, 0.0f);
            float inter = dx * dy;
            iou[s] = fast_div(inter, (area_t + area_p[s]) - inter);
            if (iou[s] > bestv[s]) { bestv[s] = iou[s]; besto[s] = o; }
        }
        float mv = fmaxf(fmaxf(iou[0], iou[1]), fmaxf(iou[2], iou[3]));
        for (int m = 1; m < 64; m <<= 1)
            mv = fmaxf(mv, __shfl_xor(mv, m, 64));
        u64 b0 = __ballot(iou[0] == mv);
        u64 b1 = __ballot(iou[1] == mv);
        u64 b2 = __ballot(iou[2] == mv);
        u64 b3 = __ballot(iou[3] == mv);
        if (lane == 0) {
            int s, l;
            if      (b0) { s = 0; l = __ffsll(b0) - 1; }
            else if (b1) { s = 1; l = __ffsll(b1) - 1; }
            else if (b2) { s = 2; l = __ffsll(b2) - 1; }
            else if (b3) { s = 3; l = __ffsll(b3) - 1; }
            else         { s = 0; l = 0; }
            u32 wp = (u32)(wbase + s * 64 + l);
            wkeys[wid][o] = ((u64)__float_as_uint(mv) << 32) | (u64)(0xFFFFFFFFu - wp);
        }
    }
#pragma unroll
    for (int s = 0; s < MPT; ++s) {
        int p = wbase + s * 64 + lane;
        btov[(size_t)b * PP + p] = bestv[s];
        btidx[(size_t)b * PP + p] = (u8)besto[s];
    }
    __syncthreads();
    if (tid < OO) {
        u64 k0 = wkeys[0][tid];
        for (int w = 1; w < 4; ++w) { u64 kw = wkeys[w][tid]; if (kw > k0) k0 = kw; }
        atomicMax(&keys[b * OO + tid], k0);
    }
}

// Parallel last-wins scatter (numpy fancy-assignment semantics).
__global__ void override_kernel(const u64* __restrict__ keys,
                                float* __restrict__ btov, u8* __restrict__ btidx) {
    const int b = blockIdx.x;
    const int o = threadIdx.x;
    u32 p = 0xFFFFFFFFu;
    if (o < OO) p = 0xFFFFFFFFu - (u32)(keys[b * OO + o] & 0xFFFFFFFFull);
    bool win = (o < OO);
    for (int o2 = 1; o2 < OO; ++o2) {
        u32 p2 = __shfl(p, o2, 64);
        if (o < o2 && p2 == p) win = false;
    }
    if (win) {
        btov[(size_t)b * PP + p] = 2.0f;
        btidx[(size_t)b * PP + p] = (u8)o;
    }
}

static __device__ __forceinline__ u32 top16bits(float v) {
    u32 u = __float_as_uint(v);
    return (v > 0.0f) ? u : 0u;
}

// Register-resident score: one thread = 4 consecutive priors (21 float4 of
// conf). Accumulates per-bin COUNT and per-bin VALUE-SUM histograms in LDS,
// flushed once per block -> no cemine array, no later data passes.
#define EL(k) ((((k) & 3) == 0) ? v[(k) >> 2].x : \
               (((k) & 3) == 1) ? v[(k) >> 2].y : \
               (((k) & 3) == 2) ? v[(k) >> 2].z : v[(k) >> 2].w)

__global__ __launch_bounds__(256) void score_kernel(
    const float* __restrict__ loc, const float* __restrict__ conf,
    const float* __restrict__ priors, const float* __restrict__ targets,
    const float* __restrict__ btov, const u8* __restrict__ btidx,
    int* __restrict__ npos, double* __restrict__ dacc,
    u32* __restrict__ whc, float* __restrict__ whs)
{
    const int b = blockIdx.y;
    const int tid = threadIdx.x;
    const int p = blockIdx.x * 1024 + tid * 4;       // 4 priors per thread
    __shared__ float tr[OO * 5];
    __shared__ __align__(16) u32 hh[WBINS];          // count hist; aliased later
    __shared__ __align__(16) float hs[WBINS];        // value-sum hist
    if (tid < OO * 5) tr[tid] = targets[(size_t)b * OO * 5 + tid];
#pragma unroll
    for (int j = 0; j < WBINS / 256; ++j) { hh[j * 256 + tid] = 0; hs[j * 256 + tid] = 0.0f; }
    __syncthreads();

    float4 ov4 = *(const float4*)(btov + (size_t)b * PP + p);
    uchar4 ox4 = *(const uchar4*)(btidx + (size_t)b * PP + p);
    const float ovv[4] = {ov4.x, ov4.y, ov4.z, ov4.w};
    const int  oidx[4] = {(int)ox4.x, (int)ox4.y, (int)ox4.z, (int)ox4.w};

    const float4* cp = (const float4*)(conf + ((size_t)b * PP + p) * NC);
    float4 v[21];
    float cev[4];
    double l_l = 0.0, pce = 0.0; int np_ = 0;

#pragma unroll
    for (int r = 0; r < 4; ++r) {
        const int jlo = (r == 0) ? 0 : ((21 * (r - 1) + 20) / 4 + 1);
        const int jhi = (21 * r + 20) / 4;
#pragma unroll
        for (int j = jlo; j <= jhi; ++j) v[j] = cp[j];

        int conft = 0;
        if (ovv[r] >= 0.5f) conft = (int)(tr[oidx[r] * 5 + 4] + 1.0f);
        const bool pos = conft > 0;

        float m = -1e30f;
#pragma unroll
        for (int c = 0; c < NC; ++c) m = fmaxf(m, EL(21 * r + c));
        float s = 0.0f, tl = 0.0f;
#pragma unroll
        for (int c = 0; c < NC; ++c) {
            float xx = EL(21 * r + c);
            s += expf(xx - m);
            if (c == conft) tl = xx;
        }
        float ce = (m + logf(s)) - tl;
        cev[r] = pos ? 0.0f : ce;

        if (pos) {
            np_ += 1; pce += (double)ce;
            int o = oidx[r];
            float mx1 = tr[o*5+0], my1 = tr[o*5+1], mx2 = tr[o*5+2], my2 = tr[o*5+3];
            float4 pr = *(const float4*)(priors + (size_t)(p + r) * 4);
            float lt0 = ((mx1 + mx2) * 0.5f - pr.x) / (0.1f * pr.z);
            float lt1 = ((my1 + my2) * 0.5f - pr.y) / (0.1f * pr.w);
            float lt2 = logf((mx2 - mx1) / pr.z) / 0.2f;
            float lt3 = logf((my2 - my1) / pr.w) / 0.2f;
            float4 l4 = *(const float4*)(loc + ((size_t)b * PP + p + r) * 4);
            float lpv[4] = {l4.x, l4.y, l4.z, l4.w};
            float lt[4] = {lt0, lt1, lt2, lt3};
#pragma unroll
            for (int i2 = 0; i2 < 4; ++i2) {
                float d = lpv[i2] - lt[i2];
                float ad = fabsf(d);
                l_l += (double)(ad < 1.0f ? 0.5f * d * d : ad - 0.5f);
            }
        }
    }

    // LDS count+sum histogram of nonzero ce (zeros = positives, uncounted)
#pragma unroll
    for (int r = 0; r < 4; ++r) {
        u32 t16 = top16bits(cev[r]) >> 16;
        if (t16 != 0) {
            int widx = ((int)t16 - WBINLO) >> 1;
            widx = widx < 0 ? 0 : (widx > WBINS - 1 ? WBINS - 1 : widx);
            atomicAdd(&hh[widx], 1u);
            atomicAdd(&hs[widx], cev[r]);
        }
    }
    __syncthreads();
#pragma unroll
    for (int j = 0; j < WBINS / 256; ++j) {
        u32 c = hh[j * 256 + tid];
        if (c) {
            atomicAdd(&whc[(size_t)b * WBINS + j * 256 + tid], c);
            atomicAdd(&whs[(size_t)b * WBINS + j * 256 + tid], hs[j * 256 + tid]);
        }
    }
    __syncthreads();                      // flush reads done; alias reductions
    double* rl = (double*)hh;             // 256 doubles (2 KB of hh)
    double* rc = (double*)hs;             // 256 doubles (2 KB of hs)
    int*    rn = (int*)(hh + 1024);       // 256 ints (upper half of hh)
    rl[tid] = l_l; rc[tid] = pce; rn[tid] = np_;
    __syncthreads();
    for (int s2 = 128; s2 > 0; s2 >>= 1) {
        if (tid < s2) { rl[tid] += rl[tid+s2]; rc[tid] += rc[tid+s2]; rn[tid] += rn[tid+s2]; }
        __syncthreads();
    }
    if (tid == 0) {
        atomicAdd(&dacc[b], rl[0]);
        atomicAdd(&dacc[BB + b], rc[0]);
        atomicAdd(&npos[b], rn[0]);
    }
}

// Single select kernel: exact threshold bin via count hist; hard-negative sum
// = exact sum of bins above + k2 * (boundary-bin mean).
__global__ __launch_bounds__(256) void selwin_kernel(
    const u32* __restrict__ whc, const float* __restrict__ whs,
    const int* __restrict__ npos, double* __restrict__ dacc)
{
    const int b = blockIdx.x, tid = threadIdx.x;
    const int lane = tid & 63, wid = tid >> 6;
    int k = npos[b] * 3; if (k > PP - 1) k = PP - 1;
    if (k <= 0) return;                       // dacc[2BB+b] stays 0
    const u32* hc = whc + (size_t)b * WBINS;
    const float* hsg = whs + (size_t)b * WBINS;

    __shared__ u32 ccnt_[WBINS / 256]; __shared__ float csum_[WBINS / 256];
    __shared__ u32 ct[256]; __shared__ float fs[256];
    __shared__ int s_cT; __shared__ u32 s_aboveC; __shared__ float s_aboveS;
    __shared__ u32 sT;

    for (int c = wid; c < WBINS / 256; c += 4) {
        u32 cnt = 0; float sm = 0.0f;
#pragma unroll
        for (int q = 0; q < 4; ++q) {
            int idx = c * 256 + q * 64 + lane;
            cnt += hc[idx];
            sm  += hsg[idx];
        }
        for (int m = 1; m < 64; m <<= 1) {
            cnt += __shfl_xor(cnt, m, 64);
            sm  += __shfl_xor(sm, m, 64);
        }
        if (lane == 0) { ccnt_[c] = cnt; csum_[c] = sm; }
    }
    if (tid == 0) sT = 0;
    __syncthreads();
    if (tid == 0) {
        u32 cum = 0; float scum = 0.0f; int cT = -1; u32 aboveC = 0; float aboveS = 0.0f;
        for (int c = WBINS / 256 - 1; c >= 0; --c) {
            if (cum + ccnt_[c] >= (u32)k) { cT = c; aboveC = cum; aboveS = scum; break; }
            cum += ccnt_[c]; scum += csum_[c];
        }
        s_cT = cT; s_aboveC = aboveC; s_aboveS = aboveS;
        if (cT < 0) dacc[2 * BB + b] = (double)scum;   // k >= all nonzero: take all
    }
    __syncthreads();
    const int cT = s_cT;
    if (cT < 0) return;
    const u32 aboveC = s_aboveC; const float aboveS = s_aboveS;

    const u32 myc = hc[cT * 256 + tid];
    const float mys = hsg[cT * 256 + tid];
    ct[tid] = myc; fs[tid] = mys;
    __syncthreads();
    for (int off = 1; off < 256; off <<= 1) {
        u32 a1 = (tid + off < 256) ? ct[tid + off] : 0;
        float a2 = (tid + off < 256) ? fs[tid + off] : 0.0f;
        __syncthreads();
        ct[tid] += a1; fs[tid] += a2;
        __syncthreads();
    }
    if (aboveC + ct[tid] >= (u32)k) atomicMax(&sT, (u32)tid);
    __syncthreads();
    const int T = (int)sT;
    if (tid == T) {
        u32 aboveBinC = aboveC + ((T < 255) ? ct[T + 1] : 0);
        float aboveBinS = aboveS + ((T < 255) ? fs[T + 1] : 0.0f);
        int k2 = k - (int)aboveBinC;
        double avg = (double)mys / (double)myc;        // boundary-bin mean
        dacc[2 * BB + b] = (double)aboveBinS + (double)k2 * avg;
    }
}

__global__ void finalize_kernel(const int* __restrict__ npos,
                                const double* __restrict__ dacc, float* __restrict__ out) {
    if (threadIdx.x == 0 && blockIdx.x == 0) {
        double N = 0.0, ll = 0.0, lc = 0.0;
        for (int b = 0; b < BB; ++b) {
            N += (double)npos[b];
            ll += dacc[b];
            lc += dacc[BB + b] + dacc[2 * BB + b];
        }
        out[0] = (float)(ll / N);
        out[1] = (float)(lc / N);
    }
}

extern "C" void kernel_launch(void* const* d_in, const int* in_sizes, int n_in,
                              void* d_out, int out_size, void* d_ws, size_t ws_size,
                              hipStream_t stream) {
    const float* loc     = (const float*)d_in[0];
    const float* conf    = (const float*)d_in[1];
    const float* priors  = (const float*)d_in[2];
    const float* targets = (const float*)d_in[3];
    char* ws = (char*)d_ws;
    u32*    whc   = (u32*)   (ws + OFF_WHC);
    float*  whs   = (float*) (ws + OFF_WHS);
    u64*    keys  = (u64*)   (ws + OFF_KEYS);
    int*    npos  = (int*)   (ws + OFF_NPOS);
    double* dacc  = (double*)(ws + OFF_DACC);
    float*  btov  = (float*) (ws + OFF_BTOV);
    u8*     btidx = (u8*)    (ws + OFF_BTIDX);
    float*  out   = (float*)d_out;

    hipMemsetAsync(ws, 0, ZERO_BYTES, stream);   // whc+whs+keys+npos+dacc (~0.53 MB)
    match_kernel<<<dim3(PP / (256 * MPT), BB), 256, 0, stream>>>(priors, targets, btov, btidx, keys);
    override_kernel<<<BB, 64, 0, stream>>>(keys, btov, btidx);
    score_kernel<<<dim3(PP / 1024, BB), 256, 0, stream>>>(loc, conf, priors, targets, btov, btidx, npos, dacc, whc, whs);
    selwin_kernel<<<BB, 256, 0, stream>>>(whc, whs, npos, dacc);
    finalize_kernel<<<1, 64, 0, stream>>>(npos, dacc, out);
}

// Round 11
// 99.211 us; speedup vs baseline: 2.9175x; 1.0564x over previous
//
#include <hip/hip_runtime.h>
#include <math.h>

#define BB 32
#define PP 32768
#define OO 50
#define NT 25            // truths per match block (2 halves)
#define NC 21
#define MPT 4            // priors per thread in match_kernel

// histogram window: float exponents [104,136), 6 mantissa bits ->
// bin = (top16 - WBINLO) >> 1, WBINS=2048. Selection exact at any bin width;
// boundary-bin mean approx error ~2e-3 of output (tol 0.35).
#define WBINLO (104 << 7)
#define WBINS  2048

typedef unsigned long long u64;
typedef unsigned int u32;
typedef unsigned char u8;

// Packed per-prior key: (iou_bits << 32) | lo, where lo = 49-o for regular
// (max lo = min o = numpy first-max argmax) and lo = 64+o for forced priors
// (2.0f bits dominate; max o = numpy last-wins scatter).
static constexpr u32 FORCED_HI = 0x40000000u;   // __float_as_uint(2.0f)
static constexpr u32 HALF_BITS = 0x3F000000u;   // __float_as_uint(0.5f)

// workspace: zero-init block first (one memset), then scratch
static constexpr size_t OFF_WHC   = 0;                            // u32[BB*WBINS] 256 KB
static constexpr size_t OFF_WHS   = OFF_WHC  + 4ull*BB*WBINS;     // f32[BB*WBINS] 256 KB
static constexpr size_t OFF_KEYS  = OFF_WHS  + 4ull*BB*WBINS;     // u64[BB*OO]
static constexpr size_t OFF_NPOS  = OFF_KEYS + 8ull*BB*OO;        // int[BB]
static constexpr size_t OFF_DACC  = OFF_NPOS + 128;               // double[3*BB]
static constexpr size_t OFF_KEY2  = ((OFF_DACC + 8ull*3*BB + 127) & ~127ull); // u64[BB*PP] 8 MB
static constexpr size_t ZERO_BYTES = OFF_KEY2 + 8ull*BB*PP;

static __device__ __forceinline__ float fast_div(float a, float b) {
    return a * __builtin_amdgcn_rcpf(b);
}

// Per (b, truth-half, 4 priors): IoU vs 25 truths. Per-prior best merged
// across halves via packed u64 atomicMax (uncontended, 2 writers/addr).
// Per-truth best prior via float butterfly + ordered ballots (smallest p).
__global__ __launch_bounds__(256) void match_kernel(
    const float* __restrict__ priors, const float* __restrict__ targets,
    u64* __restrict__ key2, u64* __restrict__ keys)
{
#pragma clang fp contract(off)
    const int b = blockIdx.y;
    const int obase = blockIdx.z * NT;
    const int tid = threadIdx.x;
    const int lane = tid & 63, wid = tid >> 6;
    const int wbase = blockIdx.x * (256 * MPT) + wid * (64 * MPT);

    __shared__ float tr[NT * 5];
    __shared__ u64 wkeys[4][NT];
    if (tid < NT * 5) tr[tid] = targets[(size_t)b * OO * 5 + obase * 5 + tid];
    __syncthreads();

    float px1[MPT], py1[MPT], px2[MPT], py2[MPT], area_p[MPT];
#pragma unroll
    for (int s = 0; s < MPT; ++s) {
        int p = wbase + s * 64 + lane;
        float4 pr = *(const float4*)(priors + (size_t)p * 4);
        px1[s] = pr.x - pr.z * 0.5f; py1[s] = pr.y - pr.w * 0.5f;
        px2[s] = pr.x + pr.z * 0.5f; py2[s] = pr.y + pr.w * 0.5f;
        area_p[s] = (px2[s] - px1[s]) * (py2[s] - py1[s]);
    }

    float bestv[MPT]; int besto[MPT];
#pragma unroll
    for (int s = 0; s < MPT; ++s) { bestv[s] = -1.0f; besto[s] = 0; }

    for (int o = 0; o < NT; ++o) {
        float tx1 = tr[o*5+0], ty1 = tr[o*5+1], tx2 = tr[o*5+2], ty2 = tr[o*5+3];
        float area_t = (tx2 - tx1) * (ty2 - ty1);
        float iou[MPT];
#pragma unroll
        for (int s = 0; s < MPT; ++s) {
            float ix1 = fmaxf(tx1, px1[s]), iy1 = fmaxf(ty1, py1[s]);
            float ix2 = fminf(tx2, px2[s]), iy2 = fminf(ty2, py2[s]);
            float dx = fmaxf(ix2 - ix1, 0.0f), dy = fmaxf(iy2 - iy1, 0.0f);
            float inter = dx * dy;
            iou[s] = fast_div(inter, (area_t + area_p[s]) - inter);
            if (iou[s] > bestv[s]) { bestv[s] = iou[s]; besto[s] = o; }
        }
        float mv = fmaxf(fmaxf(iou[0], iou[1]), fmaxf(iou[2], iou[3]));
        for (int m = 1; m < 64; m <<= 1)
            mv = fmaxf(mv, __shfl_xor(mv, m, 64));
        u64 b0 = __ballot(iou[0] == mv);
        u64 b1 = __ballot(iou[1] == mv);
        u64 b2 = __ballot(iou[2] == mv);
        u64 b3 = __ballot(iou[3] == mv);
        if (lane == 0) {
            int s, l;
            if      (b0) { s = 0; l = __ffsll(b0) - 1; }
            else if (b1) { s = 1; l = __ffsll(b1) - 1; }
            else if (b2) { s = 2; l = __ffsll(b2) - 1; }
            else if (b3) { s = 3; l = __ffsll(b3) - 1; }
            else         { s = 0; l = 0; }
            u32 wp = (u32)(wbase + s * 64 + l);
            wkeys[wid][o] = ((u64)__float_as_uint(mv) << 32) | (u64)(0xFFFFFFFFu - wp);
        }
    }
    // merge per-prior best across truth-halves (uncontended u64 atomicMax)
#pragma unroll
    for (int s = 0; s < MPT; ++s) {
        int p = wbase + s * 64 + lane;
        u64 key = ((u64)__float_as_uint(bestv[s]) << 32)
                | (u64)(u32)(49 - (obase + besto[s]));
        atomicMax(&key2[(size_t)b * PP + p], key);
    }
    __syncthreads();
    if (tid < NT) {
        u64 k0 = wkeys[0][tid];
        for (int w = 1; w < 4; ++w) { u64 kw = wkeys[w][tid]; if (kw > k0) k0 = kw; }
        atomicMax(&keys[b * OO + obase + tid], k0);
    }
}

// Forced-prior override: atomicMax with dominant key; max o == numpy
// last-wins fancy-assignment. No dedup needed.
__global__ void override_kernel(const u64* __restrict__ keys, u64* __restrict__ key2) {
    const int b = blockIdx.x;
    const int o = threadIdx.x;
    if (o < OO) {
        u32 p = 0xFFFFFFFFu - (u32)(keys[b * OO + o] & 0xFFFFFFFFull);
        atomicMax(&key2[(size_t)b * PP + p],
                  ((u64)FORCED_HI << 32) | (u64)(u32)(64 + o));
    }
}

static __device__ __forceinline__ u32 top16bits(float v) {
    u32 u = __float_as_uint(v);
    return (v > 0.0f) ? u : 0u;
}

// Register-resident score: one thread = 4 consecutive priors (21 float4 of
// conf). Decodes packed match keys; accumulates per-bin COUNT and VALUE-SUM
// histograms in LDS, flushed once per block.
#define EL(k) ((((k) & 3) == 0) ? v[(k) >> 2].x : \
               (((k) & 3) == 1) ? v[(k) >> 2].y : \
               (((k) & 3) == 2) ? v[(k) >> 2].z : v[(k) >> 2].w)

__global__ __launch_bounds__(256) void score_kernel(
    const float* __restrict__ loc, const float* __restrict__ conf,
    const float* __restrict__ priors, const float* __restrict__ targets,
    const u64* __restrict__ key2,
    int* __restrict__ npos, double* __restrict__ dacc,
    u32* __restrict__ whc, float* __restrict__ whs)
{
    const int b = blockIdx.y;
    const int tid = threadIdx.x;
    const int p = blockIdx.x * 1024 + tid * 4;       // 4 priors per thread
    __shared__ float tr[OO * 5];
    __shared__ __align__(16) u32 hh[WBINS];          // count hist; aliased later
    __shared__ __align__(16) float hs[WBINS];        // value-sum hist
    if (tid < OO * 5) tr[tid] = targets[(size_t)b * OO * 5 + tid];
#pragma unroll
    for (int j = 0; j < WBINS / 256; ++j) { hh[j * 256 + tid] = 0; hs[j * 256 + tid] = 0.0f; }
    __syncthreads();

    ulonglong2 k01 = *(const ulonglong2*)(key2 + (size_t)b * PP + p);
    ulonglong2 k23 = *(const ulonglong2*)(key2 + (size_t)b * PP + p + 2);
    const u64 kk[4] = {k01.x, k01.y, k23.x, k23.y};

    const float4* cp = (const float4*)(conf + ((size_t)b * PP + p) * NC);
    float4 v[21];
    float cev[4];
    double l_l = 0.0, pce = 0.0; int np_ = 0;

#pragma unroll
    for (int r = 0; r < 4; ++r) {
        const int jlo = (r == 0) ? 0 : ((21 * (r - 1) + 20) / 4 + 1);
        const int jhi = (21 * r + 20) / 4;
#pragma unroll
        for (int j = jlo; j <= jhi; ++j) v[j] = cp[j];

        const u32 hi = (u32)(kk[r] >> 32);
        const u32 lo = (u32)kk[r];
        const bool forced = lo >= 64u;
        const int o = forced ? (int)(lo - 64u) : (int)(49u - lo);
        const bool pos = forced || hi >= HALF_BITS;   // bit-monotone iou >= 0.5
        const int conft = pos ? (int)(tr[o * 5 + 4] + 1.0f) : 0;

        float m = -1e30f;
#pragma unroll
        for (int c = 0; c < NC; ++c) m = fmaxf(m, EL(21 * r + c));
        float s = 0.0f, tl = 0.0f;
#pragma unroll
        for (int c = 0; c < NC; ++c) {
            float xx = EL(21 * r + c);
            s += expf(xx - m);
            if (c == conft) tl = xx;
        }
        float ce = (m + logf(s)) - tl;
        cev[r] = pos ? 0.0f : ce;

        if (pos) {
            np_ += 1; pce += (double)ce;
            float mx1 = tr[o*5+0], my1 = tr[o*5+1], mx2 = tr[o*5+2], my2 = tr[o*5+3];
            float4 pr = *(const float4*)(priors + (size_t)(p + r) * 4);
            float lt0 = ((mx1 + mx2) * 0.5f - pr.x) / (0.1f * pr.z);
            float lt1 = ((my1 + my2) * 0.5f - pr.y) / (0.1f * pr.w);
            float lt2 = logf((mx2 - mx1) / pr.z) / 0.2f;
            float lt3 = logf((my2 - my1) / pr.w) / 0.2f;
            float4 l4 = *(const float4*)(loc + ((size_t)b * PP + p + r) * 4);
            float lpv[4] = {l4.x, l4.y, l4.z, l4.w};
            float lt[4] = {lt0, lt1, lt2, lt3};
#pragma unroll
            for (int i2 = 0; i2 < 4; ++i2) {
                float d = lpv[i2] - lt[i2];
                float ad = fabsf(d);
                l_l += (double)(ad < 1.0f ? 0.5f * d * d : ad - 0.5f);
            }
        }
    }

    // LDS count+sum histogram of nonzero ce (zeros = positives, uncounted)
#pragma unroll
    for (int r = 0; r < 4; ++r) {
        u32 t16 = top16bits(cev[r]) >> 16;
        if (t16 != 0) {
            int widx = ((int)t16 - WBINLO) >> 1;
            widx = widx < 0 ? 0 : (widx > WBINS - 1 ? WBINS - 1 : widx);
            atomicAdd(&hh[widx], 1u);
            atomicAdd(&hs[widx], cev[r]);
        }
    }
    __syncthreads();
#pragma unroll
    for (int j = 0; j < WBINS / 256; ++j) {
        u32 c = hh[j * 256 + tid];
        if (c) {
            atomicAdd(&whc[(size_t)b * WBINS + j * 256 + tid], c);
            atomicAdd(&whs[(size_t)b * WBINS + j * 256 + tid], hs[j * 256 + tid]);
        }
    }
    __syncthreads();                      // flush reads done; alias reductions
    double* rl = (double*)hh;             // 256 doubles (2 KB of hh)
    double* rc = (double*)hs;             // 256 doubles (2 KB of hs)
    int*    rn = (int*)(hh + 1024);       // 256 ints (upper half of hh)
    rl[tid] = l_l; rc[tid] = pce; rn[tid] = np_;
    __syncthreads();
    for (int s2 = 128; s2 > 0; s2 >>= 1) {
        if (tid < s2) { rl[tid] += rl[tid+s2]; rc[tid] += rc[tid+s2]; rn[tid] += rn[tid+s2]; }
        __syncthreads();
    }
    if (tid == 0) {
        atomicAdd(&dacc[b], rl[0]);
        atomicAdd(&dacc[BB + b], rc[0]);
        atomicAdd(&npos[b], rn[0]);
    }
}

// Single select kernel: exact threshold bin via count hist; hard-negative sum
// = exact sum of bins above + k2 * (boundary-bin mean).
__global__ __launch_bounds__(256) void selwin_kernel(
    const u32* __restrict__ whc, const float* __restrict__ whs,
    const int* __restrict__ npos, double* __restrict__ dacc)
{
    const int b = blockIdx.x, tid = threadIdx.x;
    const int lane = tid & 63, wid = tid >> 6;
    int k = npos[b] * 3; if (k > PP - 1) k = PP - 1;
    if (k <= 0) return;                       // dacc[2BB+b] stays 0
    const u32* hc = whc + (size_t)b * WBINS;
    const float* hsg = whs + (size_t)b * WBINS;

    __shared__ u32 ccnt_[WBINS / 256]; __shared__ float csum_[WBINS / 256];
    __shared__ u32 ct[256]; __shared__ float fs[256];
    __shared__ int s_cT; __shared__ u32 s_aboveC; __shared__ float s_aboveS;
    __shared__ u32 sT;

    for (int c = wid; c < WBINS / 256; c += 4) {
        u32 cnt = 0; float sm = 0.0f;
#pragma unroll
        for (int q = 0; q < 4; ++q) {
            int idx = c * 256 + q * 64 + lane;
            cnt += hc[idx];
            sm  += hsg[idx];
        }
        for (int m = 1; m < 64; m <<= 1) {
            cnt += __shfl_xor(cnt, m, 64);
            sm  += __shfl_xor(sm, m, 64);
        }
        if (lane == 0) { ccnt_[c] = cnt; csum_[c] = sm; }
    }
    if (tid == 0) sT = 0;
    __syncthreads();
    if (tid == 0) {
        u32 cum = 0; float scum = 0.0f; int cT = -1; u32 aboveC = 0; float aboveS = 0.0f;
        for (int c = WBINS / 256 - 1; c >= 0; --c) {
            if (cum + ccnt_[c] >= (u32)k) { cT = c; aboveC = cum; aboveS = scum; break; }
            cum += ccnt_[c]; scum += csum_[c];
        }
        s_cT = cT; s_aboveC = aboveC; s_aboveS = aboveS;
        if (cT < 0) dacc[2 * BB + b] = (double)scum;   // k >= all nonzero: take all
    }
    __syncthreads();
    const int cT = s_cT;
    if (cT < 0) return;
    const u32 aboveC = s_aboveC; const float aboveS = s_aboveS;

    const u32 myc = hc[cT * 256 + tid];
    const float mys = hsg[cT * 256 + tid];
    ct[tid] = myc; fs[tid] = mys;
    __syncthreads();
    for (int off = 1; off < 256; off <<= 1) {
        u32 a1 = (tid + off < 256) ? ct[tid + off] : 0;
        float a2 = (tid + off < 256) ? fs[tid + off] : 0.0f;
        __syncthreads();
        ct[tid] += a1; fs[tid] += a2;
        __syncthreads();
    }
    if (aboveC + ct[tid] >= (u32)k) atomicMax(&sT, (u32)tid);
    __syncthreads();
    const int T = (int)sT;
    if (tid == T) {
        u32 aboveBinC = aboveC + ((T < 255) ? ct[T + 1] : 0);
        float aboveBinS = aboveS + ((T < 255) ? fs[T + 1] : 0.0f);
        int k2 = k - (int)aboveBinC;
        double avg = (double)mys / (double)myc;        // boundary-bin mean
        dacc[2 * BB + b] = (double)aboveBinS + (double)k2 * avg;
    }
}

__global__ void finalize_kernel(const int* __restrict__ npos,
                                const double* __restrict__ dacc, float* __restrict__ out) {
    if (threadIdx.x == 0 && blockIdx.x == 0) {
        double N = 0.0, ll = 0.0, lc = 0.0;
        for (int b = 0; b < BB; ++b) {
            N += (double)npos[b];
            ll += dacc[b];
            lc += dacc[BB + b] + dacc[2 * BB + b];
        }
        out[0] = (float)(ll / N);
        out[1] = (float)(lc / N);
    }
}

extern "C" void kernel_launch(void* const* d_in, const int* in_sizes, int n_in,
                              void* d_out, int out_size, void* d_ws, size_t ws_size,
                              hipStream_t stream) {
    const float* loc     = (const float*)d_in[0];
    const float* conf    = (const float*)d_in[1];
    const float* priors  = (const float*)d_in[2];
    const float* targets = (const float*)d_in[3];
    char* ws = (char*)d_ws;
    u32*    whc   = (u32*)   (ws + OFF_WHC);
    float*  whs   = (float*) (ws + OFF_WHS);
    u64*    keys  = (u64*)   (ws + OFF_KEYS);
    int*    npos  = (int*)   (ws + OFF_NPOS);
    double* dacc  = (double*)(ws + OFF_DACC);
    u64*    key2  = (u64*)   (ws + OFF_KEY2);
    float*  out   = (float*)d_out;

    hipMemsetAsync(ws, 0, ZERO_BYTES, stream);   // whc+whs+keys+npos+dacc+key2 (~8.5 MB)
    match_kernel<<<dim3(PP / (256 * MPT), BB, 2), 256, 0, stream>>>(priors, targets, key2, keys);
    override_kernel<<<BB, 64, 0, stream>>>(keys, key2);
    score_kernel<<<dim3(PP / 1024, BB), 256, 0, stream>>>(loc, conf, priors, targets, key2, npos, dacc, whc, whs);
    selwin_kernel<<<BB, 256, 0, stream>>>(whc, whs, npos, dacc);
    finalize_kernel<<<1, 64, 0, stream>>>(npos, dacc, out);
}

// Round 12
// 98.968 us; speedup vs baseline: 2.9247x; 1.0025x over previous
//
#include <hip/hip_runtime.h>
#include <math.h>

#define BB 32
#define PP 32768
#define OO 50
#define NT 25            // truths per match block (2 halves)
#define NC 21
#define MPT 4            // priors per thread in match_kernel

// histogram window: float exponents [104,136), 6 mantissa bits ->
// bin = (top16 - WBINLO) >> 1, WBINS=2048. Selection exact at any bin width;
// boundary-bin mean approx error ~2e-3 of output (tol 0.35).
#define WBINLO (104 << 7)
#define WBINS  2048

typedef unsigned long long u64;
typedef unsigned int u32;
typedef unsigned char u8;

// Packed per-prior key: (iou_bits << 32) | lo, where lo = 49-o for regular
// (max lo = min o = numpy first-max argmax) and lo = 64+o for forced priors
// (2.0f bits dominate; max o = numpy last-wins scatter).
static constexpr u32 FORCED_HI = 0x40000000u;   // __float_as_uint(2.0f)
static constexpr u32 HALF_BITS = 0x3F000000u;   // __float_as_uint(0.5f)

// workspace: zero-init block [0, ZERO_BYTES) via zero_kernel, then scratch
static constexpr size_t OFF_WHC   = 0;                            // u32[BB*WBINS] 256 KB
static constexpr size_t OFF_WHS   = OFF_WHC  + 4ull*BB*WBINS;     // f32[BB*WBINS] 256 KB
static constexpr size_t OFF_KEYS  = OFF_WHS  + 4ull*BB*WBINS;     // u64[BB*OO]
static constexpr size_t OFF_NPOS  = OFF_KEYS + 8ull*BB*OO;        // int[BB]
static constexpr size_t OFF_DACC  = OFF_NPOS + 128;               // double[3*BB]
static constexpr size_t OFF_KEY2  = ((OFF_DACC + 8ull*3*BB + 127) & ~127ull); // u64[BB*PP] 8 MB
static constexpr size_t ZERO_BYTES = OFF_KEY2 + 8ull*BB*PP;       // ~9.05 MB, 16B-aligned

// Grid-stride 16B fill: replaces hipMemsetAsync, whose runtime fill kernel
// ran this 8.5MB region at ~170 GB/s (latency-bound, ~50us/replay).
__global__ __launch_bounds__(256) void zero_kernel(ulonglong2* __restrict__ dst, size_t n16) {
    size_t i = (size_t)blockIdx.x * 256 + threadIdx.x;
    if (i < n16) dst[i] = make_ulonglong2(0ull, 0ull);
}

static __device__ __forceinline__ float fast_div(float a, float b) {
    return a * __builtin_amdgcn_rcpf(b);
}

// Per (b, truth-half, 4 priors): IoU vs 25 truths. Per-prior best merged
// across halves via packed u64 atomicMax (uncontended, 2 writers/addr).
// Per-truth best prior via float butterfly + ordered ballots (smallest p).
__global__ __launch_bounds__(256) void match_kernel(
    const float* __restrict__ priors, const float* __restrict__ targets,
    u64* __restrict__ key2, u64* __restrict__ keys)
{
#pragma clang fp contract(off)
    const int b = blockIdx.y;
    const int obase = blockIdx.z * NT;
    const int tid = threadIdx.x;
    const int lane = tid & 63, wid = tid >> 6;
    const int wbase = blockIdx.x * (256 * MPT) + wid * (64 * MPT);

    __shared__ float tr[NT * 5];
    __shared__ u64 wkeys[4][NT];
    if (tid < NT * 5) tr[tid] = targets[(size_t)b * OO * 5 + obase * 5 + tid];
    __syncthreads();

    float px1[MPT], py1[MPT], px2[MPT], py2[MPT], area_p[MPT];
#pragma unroll
    for (int s = 0; s < MPT; ++s) {
        int p = wbase + s * 64 + lane;
        float4 pr = *(const float4*)(priors + (size_t)p * 4);
        px1[s] = pr.x - pr.z * 0.5f; py1[s] = pr.y - pr.w * 0.5f;
        px2[s] = pr.x + pr.z * 0.5f; py2[s] = pr.y + pr.w * 0.5f;
        area_p[s] = (px2[s] - px1[s]) * (py2[s] - py1[s]);
    }

    float bestv[MPT]; int besto[MPT];
#pragma unroll
    for (int s = 0; s < MPT; ++s) { bestv[s] = -1.0f; besto[s] = 0; }

    for (int o = 0; o < NT; ++o) {
        float tx1 = tr[o*5+0], ty1 = tr[o*5+1], tx2 = tr[o*5+2], ty2 = tr[o*5+3];
        float area_t = (tx2 - tx1) * (ty2 - ty1);
        float iou[MPT];
#pragma unroll
        for (int s = 0; s < MPT; ++s) {
            float ix1 = fmaxf(tx1, px1[s]), iy1 = fmaxf(ty1, py1[s]);
            float ix2 = fminf(tx2, px2[s]), iy2 = fminf(ty2, py2[s]);
            float dx = fmaxf(ix2 - ix1, 0.0f), dy = fmaxf(iy2 - iy1, 0.0f);
            float inter = dx * dy;
            iou[s] = fast_div(inter, (area_t + area_p[s]) - inter);
            if (iou[s] > bestv[s]) { bestv[s] = iou[s]; besto[s] = o; }
        }
        float mv = fmaxf(fmaxf(iou[0], iou[1]), fmaxf(iou[2], iou[3]));
        for (int m = 1; m < 64; m <<= 1)
            mv = fmaxf(mv, __shfl_xor(mv, m, 64));
        u64 b0 = __ballot(iou[0] == mv);
        u64 b1 = __ballot(iou[1] == mv);
        u64 b2 = __ballot(iou[2] == mv);
        u64 b3 = __ballot(iou[3] == mv);
        if (lane == 0) {
            int s, l;
            if      (b0) { s = 0; l = __ffsll(b0) - 1; }
            else if (b1) { s = 1; l = __ffsll(b1) - 1; }
            else if (b2) { s = 2; l = __ffsll(b2) - 1; }
            else if (b3) { s = 3; l = __ffsll(b3) - 1; }
            else         { s = 0; l = 0; }
            u32 wp = (u32)(wbase + s * 64 + l);
            wkeys[wid][o] = ((u64)__float_as_uint(mv) << 32) | (u64)(0xFFFFFFFFu - wp);
        }
    }
    // merge per-prior best across truth-halves (uncontended u64 atomicMax)
#pragma unroll
    for (int s = 0; s < MPT; ++s) {
        int p = wbase + s * 64 + lane;
        u64 key = ((u64)__float_as_uint(bestv[s]) << 32)
                | (u64)(u32)(49 - (obase + besto[s]));
        atomicMax(&key2[(size_t)b * PP + p], key);
    }
    __syncthreads();
    if (tid < NT) {
        u64 k0 = wkeys[0][tid];
        for (int w = 1; w < 4; ++w) { u64 kw = wkeys[w][tid]; if (kw > k0) k0 = kw; }
        atomicMax(&keys[b * OO + obase + tid], k0);
    }
}

// Forced-prior override: atomicMax with dominant key; max o == numpy
// last-wins fancy-assignment. No dedup needed.
__global__ void override_kernel(const u64* __restrict__ keys, u64* __restrict__ key2) {
    const int b = blockIdx.x;
    const int o = threadIdx.x;
    if (o < OO) {
        u32 p = 0xFFFFFFFFu - (u32)(keys[b * OO + o] & 0xFFFFFFFFull);
        atomicMax(&key2[(size_t)b * PP + p],
                  ((u64)FORCED_HI << 32) | (u64)(u32)(64 + o));
    }
}

static __device__ __forceinline__ u32 top16bits(float v) {
    u32 u = __float_as_uint(v);
    return (v > 0.0f) ? u : 0u;
}

// Register-resident score: one thread = 4 consecutive priors (21 float4 of
// conf). Decodes packed match keys; accumulates per-bin COUNT and VALUE-SUM
// histograms in LDS, flushed once per block.
#define EL(k) ((((k) & 3) == 0) ? v[(k) >> 2].x : \
               (((k) & 3) == 1) ? v[(k) >> 2].y : \
               (((k) & 3) == 2) ? v[(k) >> 2].z : v[(k) >> 2].w)

__global__ __launch_bounds__(256) void score_kernel(
    const float* __restrict__ loc, const float* __restrict__ conf,
    const float* __restrict__ priors, const float* __restrict__ targets,
    const u64* __restrict__ key2,
    int* __restrict__ npos, double* __restrict__ dacc,
    u32* __restrict__ whc, float* __restrict__ whs)
{
    const int b = blockIdx.y;
    const int tid = threadIdx.x;
    const int p = blockIdx.x * 1024 + tid * 4;       // 4 priors per thread
    __shared__ float tr[OO * 5];
    __shared__ __align__(16) u32 hh[WBINS];          // count hist; aliased later
    __shared__ __align__(16) float hs[WBINS];        // value-sum hist
    if (tid < OO * 5) tr[tid] = targets[(size_t)b * OO * 5 + tid];
#pragma unroll
    for (int j = 0; j < WBINS / 256; ++j) { hh[j * 256 + tid] = 0; hs[j * 256 + tid] = 0.0f; }
    __syncthreads();

    ulonglong2 k01 = *(const ulonglong2*)(key2 + (size_t)b * PP + p);
    ulonglong2 k23 = *(const ulonglong2*)(key2 + (size_t)b * PP + p + 2);
    const u64 kk[4] = {k01.x, k01.y, k23.x, k23.y};

    const float4* cp = (const float4*)(conf + ((size_t)b * PP + p) * NC);
    float4 v[21];
    float cev[4];
    double l_l = 0.0, pce = 0.0; int np_ = 0;

#pragma unroll
    for (int r = 0; r < 4; ++r) {
        const int jlo = (r == 0) ? 0 : ((21 * (r - 1) + 20) / 4 + 1);
        const int jhi = (21 * r + 20) / 4;
#pragma unroll
        for (int j = jlo; j <= jhi; ++j) v[j] = cp[j];

        const u32 hi = (u32)(kk[r] >> 32);
        const u32 lo = (u32)kk[r];
        const bool forced = lo >= 64u;
        const int o = forced ? (int)(lo - 64u) : (int)(49u - lo);
        const bool pos = forced || hi >= HALF_BITS;   // bit-monotone iou >= 0.5
        const int conft = pos ? (int)(tr[o * 5 + 4] + 1.0f) : 0;

        float m = -1e30f;
#pragma unroll
        for (int c = 0; c < NC; ++c) m = fmaxf(m, EL(21 * r + c));
        float s = 0.0f, tl = 0.0f;
#pragma unroll
        for (int c = 0; c < NC; ++c) {
            float xx = EL(21 * r + c);
            s += expf(xx - m);
            if (c == conft) tl = xx;
        }
        float ce = (m + logf(s)) - tl;
        cev[r] = pos ? 0.0f : ce;

        if (pos) {
            np_ += 1; pce += (double)ce;
            float mx1 = tr[o*5+0], my1 = tr[o*5+1], mx2 = tr[o*5+2], my2 = tr[o*5+3];
            float4 pr = *(const float4*)(priors + (size_t)(p + r) * 4);
            float lt0 = ((mx1 + mx2) * 0.5f - pr.x) / (0.1f * pr.z);
            float lt1 = ((my1 + my2) * 0.5f - pr.y) / (0.1f * pr.w);
            float lt2 = logf((mx2 - mx1) / pr.z) / 0.2f;
            float lt3 = logf((my2 - my1) / pr.w) / 0.2f;
            float4 l4 = *(const float4*)(loc + ((size_t)b * PP + p + r) * 4);
            float lpv[4] = {l4.x, l4.y, l4.z, l4.w};
            float lt[4] = {lt0, lt1, lt2, lt3};
#pragma unroll
            for (int i2 = 0; i2 < 4; ++i2) {
                float d = lpv[i2] - lt[i2];
                float ad = fabsf(d);
                l_l += (double)(ad < 1.0f ? 0.5f * d * d : ad - 0.5f);
            }
        }
    }

    // LDS count+sum histogram of nonzero ce (zeros = positives, uncounted)
#pragma unroll
    for (int r = 0; r < 4; ++r) {
        u32 t16 = top16bits(cev[r]) >> 16;
        if (t16 != 0) {
            int widx = ((int)t16 - WBINLO) >> 1;
            widx = widx < 0 ? 0 : (widx > WBINS - 1 ? WBINS - 1 : widx);
            atomicAdd(&hh[widx], 1u);
            atomicAdd(&hs[widx], cev[r]);
        }
    }
    __syncthreads();
#pragma unroll
    for (int j = 0; j < WBINS / 256; ++j) {
        u32 c = hh[j * 256 + tid];
        if (c) {
            atomicAdd(&whc[(size_t)b * WBINS + j * 256 + tid], c);
            atomicAdd(&whs[(size_t)b * WBINS + j * 256 + tid], hs[j * 256 + tid]);
        }
    }
    __syncthreads();                      // flush reads done; alias reductions
    double* rl = (double*)hh;             // 256 doubles (2 KB of hh)
    double* rc = (double*)hs;             // 256 doubles (2 KB of hs)
    int*    rn = (int*)(hh + 1024);       // 256 ints (upper half of hh)
    rl[tid] = l_l; rc[tid] = pce; rn[tid] = np_;
    __syncthreads();
    for (int s2 = 128; s2 > 0; s2 >>= 1) {
        if (tid < s2) { rl[tid] += rl[tid+s2]; rc[tid] += rc[tid+s2]; rn[tid] += rn[tid+s2]; }
        __syncthreads();
    }
    if (tid == 0) {
        atomicAdd(&dacc[b], rl[0]);
        atomicAdd(&dacc[BB + b], rc[0]);
        atomicAdd(&npos[b], rn[0]);
    }
}

// Single select kernel: exact threshold bin via count hist; hard-negative sum
// = exact sum of bins above + k2 * (boundary-bin mean).
__global__ __launch_bounds__(256) void selwin_kernel(
    const u32* __restrict__ whc, const float* __restrict__ whs,
    const int* __restrict__ npos, double* __restrict__ dacc)
{
    const int b = blockIdx.x, tid = threadIdx.x;
    const int lane = tid & 63, wid = tid >> 6;
    int k = npos[b] * 3; if (k > PP - 1) k = PP - 1;
    if (k <= 0) return;                       // dacc[2BB+b] stays 0
    const u32* hc = whc + (size_t)b * WBINS;
    const float* hsg = whs + (size_t)b * WBINS;

    __shared__ u32 ccnt_[WBINS / 256]; __shared__ float csum_[WBINS / 256];
    __shared__ u32 ct[256]; __shared__ float fs[256];
    __shared__ int s_cT; __shared__ u32 s_aboveC; __shared__ float s_aboveS;
    __shared__ u32 sT;

    for (int c = wid; c < WBINS / 256; c += 4) {
        u32 cnt = 0; float sm = 0.0f;
#pragma unroll
        for (int q = 0; q < 4; ++q) {
            int idx = c * 256 + q * 64 + lane;
            cnt += hc[idx];
            sm  += hsg[idx];
        }
        for (int m = 1; m < 64; m <<= 1) {
            cnt += __shfl_xor(cnt, m, 64);
            sm  += __shfl_xor(sm, m, 64);
        }
        if (lane == 0) { ccnt_[c] = cnt; csum_[c] = sm; }
    }
    if (tid == 0) sT = 0;
    __syncthreads();
    if (tid == 0) {
        u32 cum = 0; float scum = 0.0f; int cT = -1; u32 aboveC = 0; float aboveS = 0.0f;
        for (int c = WBINS / 256 - 1; c >= 0; --c) {
            if (cum + ccnt_[c] >= (u32)k) { cT = c; aboveC = cum; aboveS = scum; break; }
            cum += ccnt_[c]; scum += csum_[c];
        }
        s_cT = cT; s_aboveC = aboveC; s_aboveS = aboveS;
        if (cT < 0) dacc[2 * BB + b] = (double)scum;   // k >= all nonzero: take all
    }
    __syncthreads();
    const int cT = s_cT;
    if (cT < 0) return;
    const u32 aboveC = s_aboveC; const float aboveS = s_aboveS;

    const u32 myc = hc[cT * 256 + tid];
    const float mys = hsg[cT * 256 + tid];
    ct[tid] = myc; fs[tid] = mys;
    __syncthreads();
    for (int off = 1; off < 256; off <<= 1) {
        u32 a1 = (tid + off < 256) ? ct[tid + off] : 0;
        float a2 = (tid + off < 256) ? fs[tid + off] : 0.0f;
        __syncthreads();
        ct[tid] += a1; fs[tid] += a2;
        __syncthreads();
    }
    if (aboveC + ct[tid] >= (u32)k) atomicMax(&sT, (u32)tid);
    __syncthreads();
    const int T = (int)sT;
    if (tid == T) {
        u32 aboveBinC = aboveC + ((T < 255) ? ct[T + 1] : 0);
        float aboveBinS = aboveS + ((T < 255) ? fs[T + 1] : 0.0f);
        int k2 = k - (int)aboveBinC;
        double avg = (double)mys / (double)myc;        // boundary-bin mean
        dacc[2 * BB + b] = (double)aboveBinS + (double)k2 * avg;
    }
}

__global__ void finalize_kernel(const int* __restrict__ npos,
                                const double* __restrict__ dacc, float* __restrict__ out) {
    if (threadIdx.x == 0 && blockIdx.x == 0) {
        double N = 0.0, ll = 0.0, lc = 0.0;
        for (int b = 0; b < BB; ++b) {
            N += (double)npos[b];
            ll += dacc[b];
            lc += dacc[BB + b] + dacc[2 * BB + b];
        }
        out[0] = (float)(ll / N);
        out[1] = (float)(lc / N);
    }
}

extern "C" void kernel_launch(void* const* d_in, const int* in_sizes, int n_in,
                              void* d_out, int out_size, void* d_ws, size_t ws_size,
                              hipStream_t stream) {
    const float* loc     = (const float*)d_in[0];
    const float* conf    = (const float*)d_in[1];
    const float* priors  = (const float*)d_in[2];
    const float* targets = (const float*)d_in[3];
    char* ws = (char*)d_ws;
    u32*    whc   = (u32*)   (ws + OFF_WHC);
    float*  whs   = (float*) (ws + OFF_WHS);
    u64*    keys  = (u64*)   (ws + OFF_KEYS);
    int*    npos  = (int*)   (ws + OFF_NPOS);
    double* dacc  = (double*)(ws + OFF_DACC);
    u64*    key2  = (u64*)   (ws + OFF_KEY2);
    float*  out   = (float*)d_out;

    const size_t n16 = ZERO_BYTES / 16;
    zero_kernel<<<(unsigned)((n16 + 255) / 256), 256, 0, stream>>>((ulonglong2*)ws, n16);
    match_kernel<<<dim3(PP / (256 * MPT), BB, 2), 256, 0, stream>>>(priors, targets, key2, keys);
    override_kernel<<<BB, 64, 0, stream>>>(keys, key2);
    score_kernel<<<dim3(PP / 1024, BB), 256, 0, stream>>>(loc, conf, priors, targets, key2, npos, dacc, whc, whs);
    selwin_kernel<<<BB, 256, 0, stream>>>(whc, whs, npos, dacc);
    finalize_kernel<<<1, 64, 0, stream>>>(npos, dacc, out);
}

// Round 13
// 98.622 us; speedup vs baseline: 2.9350x; 1.0035x over previous
//
#include <hip/hip_runtime.h>
#include <math.h>

#define BB 32
#define PP 32768
#define OO 50
#define NT 25            // truths per match block (2 halves)
#define NC 21
#define MPT 4            // priors per thread in match_kernel

// histogram window: float exponents [104,136), 6 mantissa bits ->
// bin = (top16 - WBINLO) >> 1, WBINS=2048. Selection exact at any bin width;
// boundary-bin mean approx error ~2e-3 of output (tol 0.35).
#define WBINLO (104 << 7)
#define WBINS  2048

typedef unsigned long long u64;
typedef unsigned int u32;
typedef unsigned char u8;

// Per-prior key: (iou_bits << 32) | (49 - o). Max over o = first-max argmax
// (larger lo = smaller o on iou ties). Halves merged in score registers.
static constexpr u32 HALF_BITS = 0x3F000000u;   // __float_as_uint(0.5f)

// workspace: zero-init block [0, ZERO_BYTES) via zero_kernel; key2 needs no
// zeroing (fully overwritten by match's plain stores).
static constexpr size_t OFF_WHC   = 0;                            // u32[BB*WBINS] 256 KB
static constexpr size_t OFF_WHS   = OFF_WHC  + 4ull*BB*WBINS;     // f32[BB*WBINS] 256 KB
static constexpr size_t OFF_KEYS  = OFF_WHS  + 4ull*BB*WBINS;     // u64[BB*OO]
static constexpr size_t OFF_NPOS  = OFF_KEYS + 8ull*BB*OO;        // int[BB]
static constexpr size_t OFF_DACC  = OFF_NPOS + 128;               // double[3*BB]
static constexpr size_t ZERO_BYTES = OFF_DACC + 8ull*3*BB;        // 537984 B (16-divisible)
static constexpr size_t OFF_KEY2  = ((ZERO_BYTES + 127) & ~127ull); // u64[2*BB*PP] 16 MB

// Grid-stride 16B fill of the small accumulator region (~0.53 MB).
__global__ __launch_bounds__(256) void zero_kernel(ulonglong2* __restrict__ dst, size_t n16) {
    size_t i = (size_t)blockIdx.x * 256 + threadIdx.x;
    if (i < n16) dst[i] = make_ulonglong2(0ull, 0ull);
}

static __device__ __forceinline__ float fast_div(float a, float b) {
    return a * __builtin_amdgcn_rcpf(b);
}

// Per (b, truth-half, 4 priors): IoU vs 25 truths. Per-prior best written
// PLAINLY to key2[half][b][p] (single writer per slot — no atomics, no zero).
// Per-truth best prior via float butterfly + ordered ballots (smallest p).
__global__ __launch_bounds__(256) void match_kernel(
    const float* __restrict__ priors, const float* __restrict__ targets,
    u64* __restrict__ key2, u64* __restrict__ keys)
{
#pragma clang fp contract(off)
    const int b = blockIdx.y;
    const int half = blockIdx.z;
    const int obase = half * NT;
    const int tid = threadIdx.x;
    const int lane = tid & 63, wid = tid >> 6;
    const int wbase = blockIdx.x * (256 * MPT) + wid * (64 * MPT);

    __shared__ float tr[NT * 5];
    __shared__ u64 wkeys[4][NT];
    if (tid < NT * 5) tr[tid] = targets[(size_t)b * OO * 5 + obase * 5 + tid];
    __syncthreads();

    float px1[MPT], py1[MPT], px2[MPT], py2[MPT], area_p[MPT];
#pragma unroll
    for (int s = 0; s < MPT; ++s) {
        int p = wbase + s * 64 + lane;
        float4 pr = *(const float4*)(priors + (size_t)p * 4);
        px1[s] = pr.x - pr.z * 0.5f; py1[s] = pr.y - pr.w * 0.5f;
        px2[s] = pr.x + pr.z * 0.5f; py2[s] = pr.y + pr.w * 0.5f;
        area_p[s] = (px2[s] - px1[s]) * (py2[s] - py1[s]);
    }

    float bestv[MPT]; int besto[MPT];
#pragma unroll
    for (int s = 0; s < MPT; ++s) { bestv[s] = -1.0f; besto[s] = 0; }

    for (int o = 0; o < NT; ++o) {
        float tx1 = tr[o*5+0], ty1 = tr[o*5+1], tx2 = tr[o*5+2], ty2 = tr[o*5+3];
        float area_t = (tx2 - tx1) * (ty2 - ty1);
        float iou[MPT];
#pragma unroll
        for (int s = 0; s < MPT; ++s) {
            float ix1 = fmaxf(tx1, px1[s]), iy1 = fmaxf(ty1, py1[s]);
            float ix2 = fminf(tx2, px2[s]), iy2 = fminf(ty2, py2[s]);
            float dx = fmaxf(ix2 - ix1, 0.0f), dy = fmaxf(iy2 - iy1, 0.0f);
            float inter = dx * dy;
            iou[s] = fast_div(inter, (area_t + area_p[s]) - inter);
            if (iou[s] > bestv[s]) { bestv[s] = iou[s]; besto[s] = o; }
        }
        float mv = fmaxf(fmaxf(iou[0], iou[1]), fmaxf(iou[2], iou[3]));
        for (int m = 1; m < 64; m <<= 1)
            mv = fmaxf(mv, __shfl_xor(mv, m, 64));
        u64 b0 = __ballot(iou[0] == mv);
        u64 b1 = __ballot(iou[1] == mv);
        u64 b2 = __ballot(iou[2] == mv);
        u64 b3 = __ballot(iou[3] == mv);
        if (lane == 0) {
            int s, l;
            if      (b0) { s = 0; l = __ffsll(b0) - 1; }
            else if (b1) { s = 1; l = __ffsll(b1) - 1; }
            else if (b2) { s = 2; l = __ffsll(b2) - 1; }
            else if (b3) { s = 3; l = __ffsll(b3) - 1; }
            else         { s = 0; l = 0; }
            u32 wp = (u32)(wbase + s * 64 + l);
            wkeys[wid][o] = ((u64)__float_as_uint(mv) << 32) | (u64)(0xFFFFFFFFu - wp);
        }
    }
    // per-prior best for this half: plain coalesced stores (single writer)
#pragma unroll
    for (int s = 0; s < MPT; ++s) {
        int p = wbase + s * 64 + lane;
        u64 key = ((u64)__float_as_uint(bestv[s]) << 32)
                | (u64)(u32)(49 - (obase + besto[s]));
        key2[((size_t)half * BB + b) * PP + p] = key;
    }
    __syncthreads();
    if (tid < NT) {
        u64 k0 = wkeys[0][tid];
        for (int w = 1; w < 4; ++w) { u64 kw = wkeys[w][tid]; if (kw > k0) k0 = kw; }
        atomicMax(&keys[b * OO + obase + tid], k0);
    }
}

static __device__ __forceinline__ u32 top16bits(float v) {
    u32 u = __float_as_uint(v);
    return (v > 0.0f) ? u : 0u;
}

static __device__ __forceinline__ u64 umax64(u64 a, u64 b) { return a > b ? a : b; }

// Register-resident score: one thread = 4 consecutive priors (21 float4 of
// conf). Merges the two truth-half keys in registers; detects forced priors
// by comparing against the 50 per-truth winners staged in LDS (ascending
// scan = numpy last-wins). Accumulates per-bin COUNT and VALUE-SUM LDS
// histograms, flushed once per block.
#define EL(k) ((((k) & 3) == 0) ? v[(k) >> 2].x : \
               (((k) & 3) == 1) ? v[(k) >> 2].y : \
               (((k) & 3) == 2) ? v[(k) >> 2].z : v[(k) >> 2].w)

__global__ __launch_bounds__(256) void score_kernel(
    const float* __restrict__ loc, const float* __restrict__ conf,
    const float* __restrict__ priors, const float* __restrict__ targets,
    const u64* __restrict__ key2, const u64* __restrict__ keys,
    int* __restrict__ npos, double* __restrict__ dacc,
    u32* __restrict__ whc, float* __restrict__ whs)
{
    const int b = blockIdx.y;
    const int tid = threadIdx.x;
    const int p = blockIdx.x * 1024 + tid * 4;       // 4 priors per thread
    __shared__ float tr[OO * 5];
    __shared__ u32 fp[OO];                           // forced prior per truth
    __shared__ __align__(16) u32 hh[WBINS];          // count hist; aliased later
    __shared__ __align__(16) float hs[WBINS];        // value-sum hist
    if (tid < OO * 5) tr[tid] = targets[(size_t)b * OO * 5 + tid];
    if (tid < OO) fp[tid] = 0xFFFFFFFFu - (u32)(keys[b * OO + tid] & 0xFFFFFFFFull);
#pragma unroll
    for (int j = 0; j < WBINS / 256; ++j) { hh[j * 256 + tid] = 0; hs[j * 256 + tid] = 0.0f; }
    __syncthreads();

    ulonglong2 a01 = *(const ulonglong2*)(key2 + (size_t)b * PP + p);
    ulonglong2 a23 = *(const ulonglong2*)(key2 + (size_t)b * PP + p + 2);
    ulonglong2 c01 = *(const ulonglong2*)(key2 + ((size_t)BB + b) * PP + p);
    ulonglong2 c23 = *(const ulonglong2*)(key2 + ((size_t)BB + b) * PP + p + 2);
    const u64 kk[4] = {umax64(a01.x, c01.x), umax64(a01.y, c01.y),
                       umax64(a23.x, c23.x), umax64(a23.y, c23.y)};

    // forced-prior detection: ascending o, overwrite = numpy last-wins scatter
    int fo[4] = {-1, -1, -1, -1};
    for (int o = 0; o < OO; ++o) {
        u32 fpo = fp[o];
#pragma unroll
        for (int r = 0; r < 4; ++r) if (fpo == (u32)(p + r)) fo[r] = o;
    }

    const float4* cp = (const float4*)(conf + ((size_t)b * PP + p) * NC);
    float4 v[21];
    float cev[4];
    double l_l = 0.0, pce = 0.0; int np_ = 0;

#pragma unroll
    for (int r = 0; r < 4; ++r) {
        const int jlo = (r == 0) ? 0 : ((21 * (r - 1) + 20) / 4 + 1);
        const int jhi = (21 * r + 20) / 4;
#pragma unroll
        for (int j = jlo; j <= jhi; ++j) v[j] = cp[j];

        const u32 hi = (u32)(kk[r] >> 32);
        const u32 lo = (u32)kk[r];
        const bool forced = fo[r] >= 0;
        const int o = forced ? fo[r] : (int)(49u - lo);
        const bool pos = forced || hi >= HALF_BITS;   // bit-monotone iou >= 0.5
        const int conft = pos ? (int)(tr[o * 5 + 4] + 1.0f) : 0;

        float m = -1e30f;
#pragma unroll
        for (int c = 0; c < NC; ++c) m = fmaxf(m, EL(21 * r + c));
        float s = 0.0f, tl = 0.0f;
#pragma unroll
        for (int c = 0; c < NC; ++c) {
            float xx = EL(21 * r + c);
            s += expf(xx - m);
            if (c == conft) tl = xx;
        }
        float ce = (m + logf(s)) - tl;
        cev[r] = pos ? 0.0f : ce;

        if (pos) {
            np_ += 1; pce += (double)ce;
            float mx1 = tr[o*5+0], my1 = tr[o*5+1], mx2 = tr[o*5+2], my2 = tr[o*5+3];
            float4 pr = *(const float4*)(priors + (size_t)(p + r) * 4);
            float lt0 = ((mx1 + mx2) * 0.5f - pr.x) / (0.1f * pr.z);
            float lt1 = ((my1 + my2) * 0.5f - pr.y) / (0.1f * pr.w);
            float lt2 = logf((mx2 - mx1) / pr.z) / 0.2f;
            float lt3 = logf((my2 - my1) / pr.w) / 0.2f;
            float4 l4 = *(const float4*)(loc + ((size_t)b * PP + p + r) * 4);
            float lpv[4] = {l4.x, l4.y, l4.z, l4.w};
            float lt[4] = {lt0, lt1, lt2, lt3};
#pragma unroll
            for (int i2 = 0; i2 < 4; ++i2) {
                float d = lpv[i2] - lt[i2];
                float ad = fabsf(d);
                l_l += (double)(ad < 1.0f ? 0.5f * d * d : ad - 0.5f);
            }
        }
    }

    // LDS count+sum histogram of nonzero ce (zeros = positives, uncounted)
#pragma unroll
    for (int r = 0; r < 4; ++r) {
        u32 t16 = top16bits(cev[r]) >> 16;
        if (t16 != 0) {
            int widx = ((int)t16 - WBINLO) >> 1;
            widx = widx < 0 ? 0 : (widx > WBINS - 1 ? WBINS - 1 : widx);
            atomicAdd(&hh[widx], 1u);
            atomicAdd(&hs[widx], cev[r]);
        }
    }
    __syncthreads();
#pragma unroll
    for (int j = 0; j < WBINS / 256; ++j) {
        u32 c = hh[j * 256 + tid];
        if (c) {
            atomicAdd(&whc[(size_t)b * WBINS + j * 256 + tid], c);
            atomicAdd(&whs[(size_t)b * WBINS + j * 256 + tid], hs[j * 256 + tid]);
        }
    }
    __syncthreads();                      // flush reads done; alias reductions
    double* rl = (double*)hh;             // 256 doubles (2 KB of hh)
    double* rc = (double*)hs;             // 256 doubles (2 KB of hs)
    int*    rn = (int*)(hh + 1024);       // 256 ints (upper half of hh)
    rl[tid] = l_l; rc[tid] = pce; rn[tid] = np_;
    __syncthreads();
    for (int s2 = 128; s2 > 0; s2 >>= 1) {
        if (tid < s2) { rl[tid] += rl[tid+s2]; rc[tid] += rc[tid+s2]; rn[tid] += rn[tid+s2]; }
        __syncthreads();
    }
    if (tid == 0) {
        atomicAdd(&dacc[b], rl[0]);
        atomicAdd(&dacc[BB + b], rc[0]);
        atomicAdd(&npos[b], rn[0]);
    }
}

// Single select kernel: exact threshold bin via count hist; hard-negative sum
// = exact sum of bins above + k2 * (boundary-bin mean).
__global__ __launch_bounds__(256) void selwin_kernel(
    const u32* __restrict__ whc, const float* __restrict__ whs,
    const int* __restrict__ npos, double* __restrict__ dacc)
{
    const int b = blockIdx.x, tid = threadIdx.x;
    const int lane = tid & 63, wid = tid >> 6;
    int k = npos[b] * 3; if (k > PP - 1) k = PP - 1;
    if (k <= 0) return;                       // dacc[2BB+b] stays 0
    const u32* hc = whc + (size_t)b * WBINS;
    const float* hsg = whs + (size_t)b * WBINS;

    __shared__ u32 ccnt_[WBINS / 256]; __shared__ float csum_[WBINS / 256];
    __shared__ u32 ct[256]; __shared__ float fs[256];
    __shared__ int s_cT; __shared__ u32 s_aboveC; __shared__ float s_aboveS;
    __shared__ u32 sT;

    for (int c = wid; c < WBINS / 256; c += 4) {
        u32 cnt = 0; float sm = 0.0f;
#pragma unroll
        for (int q = 0; q < 4; ++q) {
            int idx = c * 256 + q * 64 + lane;
            cnt += hc[idx];
            sm  += hsg[idx];
        }
        for (int m = 1; m < 64; m <<= 1) {
            cnt += __shfl_xor(cnt, m, 64);
            sm  += __shfl_xor(sm, m, 64);
        }
        if (lane == 0) { ccnt_[c] = cnt; csum_[c] = sm; }
    }
    if (tid == 0) sT = 0;
    __syncthreads();
    if (tid == 0) {
        u32 cum = 0; float scum = 0.0f; int cT = -1; u32 aboveC = 0; float aboveS = 0.0f;
        for (int c = WBINS / 256 - 1; c >= 0; --c) {
            if (cum + ccnt_[c] >= (u32)k) { cT = c; aboveC = cum; aboveS = scum; break; }
            cum += ccnt_[c]; scum += csum_[c];
        }
        s_cT = cT; s_aboveC = aboveC; s_aboveS = aboveS;
        if (cT < 0) dacc[2 * BB + b] = (double)scum;   // k >= all nonzero: take all
    }
    __syncthreads();
    const int cT = s_cT;
    if (cT < 0) return;
    const u32 aboveC = s_aboveC; const float aboveS = s_aboveS;

    const u32 myc = hc[cT * 256 + tid];
    const float mys = hsg[cT * 256 + tid];
    ct[tid] = myc; fs[tid] = mys;
    __syncthreads();
    for (int off = 1; off < 256; off <<= 1) {
        u32 a1 = (tid + off < 256) ? ct[tid + off] : 0;
        float a2 = (tid + off < 256) ? fs[tid + off] : 0.0f;
        __syncthreads();
        ct[tid] += a1; fs[tid] += a2;
        __syncthreads();
    }
    if (aboveC + ct[tid] >= (u32)k) atomicMax(&sT, (u32)tid);
    __syncthreads();
    const int T = (int)sT;
    if (tid == T) {
        u32 aboveBinC = aboveC + ((T < 255) ? ct[T + 1] : 0);
        float aboveBinS = aboveS + ((T < 255) ? fs[T + 1] : 0.0f);
        int k2 = k - (int)aboveBinC;
        double avg = (double)mys / (double)myc;        // boundary-bin mean
        dacc[2 * BB + b] = (double)aboveBinS + (double)k2 * avg;
    }
}

__global__ void finalize_kernel(const int* __restrict__ npos,
                                const double* __restrict__ dacc, float* __restrict__ out) {
    if (threadIdx.x == 0 && blockIdx.x == 0) {
        double N = 0.0, ll = 0.0, lc = 0.0;
        for (int b = 0; b < BB; ++b) {
            N += (double)npos[b];
            ll += dacc[b];
            lc += dacc[BB + b] + dacc[2 * BB + b];
        }
        out[0] = (float)(ll / N);
        out[1] = (float)(lc / N);
    }
}

extern "C" void kernel_launch(void* const* d_in, const int* in_sizes, int n_in,
                              void* d_out, int out_size, void* d_ws, size_t ws_size,
                              hipStream_t stream) {
    const float* loc     = (const float*)d_in[0];
    const float* conf    = (const float*)d_in[1];
    const float* priors  = (const float*)d_in[2];
    const float* targets = (const float*)d_in[3];
    char* ws = (char*)d_ws;
    u32*    whc   = (u32*)   (ws + OFF_WHC);
    float*  whs   = (float*) (ws + OFF_WHS);
    u64*    keys  = (u64*)   (ws + OFF_KEYS);
    int*    npos  = (int*)   (ws + OFF_NPOS);
    double* dacc  = (double*)(ws + OFF_DACC);
    u64*    key2  = (u64*)   (ws + OFF_KEY2);
    float*  out   = (float*)d_out;

    const size_t n16 = ZERO_BYTES / 16;                     // ~0.53 MB only
    zero_kernel<<<(unsigned)((n16 + 255) / 256), 256, 0, stream>>>((ulonglong2*)ws, n16);
    match_kernel<<<dim3(PP / (256 * MPT), BB, 2), 256, 0, stream>>>(priors, targets, key2, keys);
    score_kernel<<<dim3(PP / 1024, BB), 256, 0, stream>>>(loc, conf, priors, targets, key2, keys, npos, dacc, whc, whs);
    selwin_kernel<<<BB, 256, 0, stream>>>(whc, whs, npos, dacc);
    finalize_kernel<<<1, 64, 0, stream>>>(npos, dacc, out);
}